// Round 1
// baseline (17506.342 us; speedup 1.0000x reference)
//
#include <hip/hip_runtime.h>
#include <hip/hip_bf16.h>

#define Bb 32
#define Nn 100
#define Cc 256
#define Mm 4096
#define Ff 2048
#define Ll 6
#define Hh 8
#define DH 32
#define KP 100
#define TT (Bb*KP)
#define LNEPS 1e-5f

typedef __hip_bfloat16 bf16;

__device__ __forceinline__ float bfu2f(unsigned short u) {
  union { unsigned u32; float f; } cv; cv.u32 = ((unsigned)u) << 16; return cv.f;
}

// ---------------- generic GEMM: out = [A(+A2)] @ W^T + bias ----------------
// A: [M,K] row-major, W: [N,K] row-major. 64x64 tile, 256 thr, 4x4/thread.
template<bool RELU, bool OBF16>
__global__ __launch_bounds__(256) void gemm_nt(
    const float* __restrict__ A, const float* __restrict__ A2,
    const float* __restrict__ Wt, const float* __restrict__ bias,
    void* __restrict__ out, int M, int N, int K)
{
  __shared__ float As[16][68];
  __shared__ float Ws[16][68];
  const int bm = blockIdx.y * 64, bn = blockIdx.x * 64;
  const int tid = threadIdx.x;
  const int kk = tid & 15, rr = tid >> 4;
  const int tx = tid & 15, ty = tid >> 4;
  float acc[4][4] = {};
  for (int k0 = 0; k0 < K; k0 += 16) {
    #pragma unroll
    for (int p = 0; p < 4; ++p) {
      int m = rr + p*16;
      int row = bm + m;
      float av = 0.f, wv = 0.f;
      bool kin = (k0 + kk) < K;
      if (row < M && kin) {
        size_t ai = (size_t)row * K + k0 + kk;
        av = A[ai];
        if (A2) av += A2[ai];
      }
      int wrow = bn + m;
      if (wrow < N && kin) wv = Wt[(size_t)wrow * K + k0 + kk];
      As[kk][m] = av;
      Ws[kk][m] = wv;
    }
    __syncthreads();
    #pragma unroll
    for (int q = 0; q < 16; ++q) {
      float a[4], w[4];
      #pragma unroll
      for (int i = 0; i < 4; ++i) a[i] = As[q][ty*4 + i];
      #pragma unroll
      for (int j = 0; j < 4; ++j) w[j] = Ws[q][tx*4 + j];
      #pragma unroll
      for (int i = 0; i < 4; ++i)
        #pragma unroll
        for (int j = 0; j < 4; ++j) acc[i][j] += a[i] * w[j];
    }
    __syncthreads();
  }
  #pragma unroll
  for (int i = 0; i < 4; ++i) {
    int row = bm + ty*4 + i;
    if (row >= M) continue;
    #pragma unroll
    for (int j = 0; j < 4; ++j) {
      int col = bn + tx*4 + j;
      if (col >= N) continue;
      float v = acc[i][j];
      if (bias) v += bias[col];
      if (RELU) v = v > 0.f ? v : 0.f;
      if (OBF16) ((bf16*)out)[(size_t)row*N + col] = __float2bfloat16(v);
      else       ((float*)out)[(size_t)row*N + col] = v;
    }
  }
}

// ---------------- small kernels ----------------
__global__ void split_subobj(const float* __restrict__ hs,
                             float* __restrict__ subf, float* __restrict__ objf) {
  int i = blockIdx.x*256 + threadIdx.x;
  if (i >= Bb*Nn*Cc) return;
  int c = i % Cc, n = (i / Cc) % Nn, b = i / (Cc*Nn);
  subf[i] = hs[((size_t)b*2*Nn + 2*n    )*Cc + c];
  objf[i] = hs[((size_t)b*2*Nn + 2*n + 1)*Cc + c];
}

__global__ __launch_bounds__(256) void l2norm_kernel(float* __restrict__ x) {
  int t = blockIdx.x, c = threadIdx.x;
  float v = x[(size_t)t*Cc + c];
  __shared__ float red[256];
  red[c] = v*v; __syncthreads();
  for (int s = 128; s > 0; s >>= 1) { if (c < s) red[c] += red[c+s]; __syncthreads(); }
  float scale = 1.f / (sqrtf(red[0]) + 1e-6f);
  x[(size_t)t*Cc + c] = v * scale;
}

__global__ __launch_bounds__(128) void importance_kernel(const float* __restrict__ se,
                                                         const float* __restrict__ oe,
                                                         float* __restrict__ imp) {
  int b = blockIdx.x / Nn, n = blockIdx.x % Nn;
  int m = threadIdx.x;
  if (m >= Nn) return;
  const float* s = se + ((size_t)b*Nn + n)*Cc;
  const float* o = oe + ((size_t)b*Nn + m)*Cc;
  float acc = 0.f;
  for (int c = 0; c < Cc; ++c) acc += s[c] * o[c];
  imp[((size_t)b*Nn + n)*Nn + m] = acc;
}

__global__ __launch_bounds__(256) void topk_kernel(const float* __restrict__ imp,
                                                   int* __restrict__ idx_out) {
  __shared__ float vals[Nn*Nn];
  __shared__ float rv[256];
  __shared__ int   ri[256];
  int b = blockIdx.x, tid = threadIdx.x;
  for (int i = tid; i < Nn*Nn; i += 256) vals[i] = imp[(size_t)b*Nn*Nn + i];
  __syncthreads();
  for (int k = 0; k < KP; ++k) {
    float bv = -1e30f; int bi = 0x7fffffff;
    for (int i = tid; i < Nn*Nn; i += 256) {
      float v = vals[i];
      if (v > bv || (v == bv && i < bi)) { bv = v; bi = i; }
    }
    rv[tid] = bv; ri[tid] = bi; __syncthreads();
    for (int s = 128; s > 0; s >>= 1) {
      if (tid < s) {
        float v2 = rv[tid+s]; int i2 = ri[tid+s];
        if (v2 > rv[tid] || (v2 == rv[tid] && i2 < ri[tid])) { rv[tid] = v2; ri[tid] = i2; }
      }
      __syncthreads();
    }
    if (tid == 0) { idx_out[b*KP + k] = ri[0]; vals[ri[0]] = -1e30f; }
    __syncthreads();
  }
}

__global__ __launch_bounds__(256) void gather_pair(const float* __restrict__ subf,
                                                   const float* __restrict__ objf,
                                                   const int* __restrict__ idx,
                                                   float* __restrict__ pc) {
  int bk = blockIdx.x;
  int b = bk / KP;
  int id = idx[bk];
  int spos = id / Nn, opos = id % Nn;
  const float* s = subf + ((size_t)b*Nn + spos)*Cc;
  const float* o = objf + ((size_t)b*Nn + opos)*Cc;
  float* dst = pc + (size_t)bk * (2*Cc);
  for (int c = threadIdx.x; c < Cc; c += 256) { dst[c] = s[c]; dst[Cc + c] = o[c]; }
}

__global__ void boxes_cat_kernel(const float* __restrict__ sb, const float* __restrict__ ob,
                                 float* __restrict__ out) {
  int i = blockIdx.x*256 + threadIdx.x;
  if (i >= TT*8) return;
  int c = i & 7, bk = i >> 3;
  out[i] = (c < 4) ? sb[bk*4 + c] : ob[bk*4 + (c - 4)];
}

__global__ __launch_bounds__(256) void ln_residual(const float* __restrict__ qin,
                                                   const float* __restrict__ delta,
                                                   const float* __restrict__ g,
                                                   const float* __restrict__ bta,
                                                   float* __restrict__ qout) {
  int t = blockIdx.x, c = threadIdx.x;
  float x = qin[(size_t)t*Cc + c] + delta[(size_t)t*Cc + c];
  __shared__ float red[256];
  red[c] = x; __syncthreads();
  for (int s = 128; s > 0; s >>= 1) { if (c < s) red[c] += red[c+s]; __syncthreads(); }
  float mean = red[0] * (1.f/Cc);
  __syncthreads();
  float d = x - mean;
  red[c] = d*d; __syncthreads();
  for (int s = 128; s > 0; s >>= 1) { if (c < s) red[c] += red[c+s]; __syncthreads(); }
  float var = red[0] * (1.f/Cc);
  qout[(size_t)t*Cc + c] = d * rsqrtf(var + LNEPS) * g[c] + bta[c];
}

// ---------------- self-attention: 100 keys, one tile ----------------
__global__ __launch_bounds__(512) void attn_sa(const float* __restrict__ qkv,
                                               float* __restrict__ out) {
  __shared__ float Kt[128][36];
  __shared__ float Vt[128][36];
  __shared__ float Qs[KP][DH];
  __shared__ float Ps[8][128];
  int bh = blockIdx.x; int b = bh >> 3, h = bh & 7;
  int tid = threadIdx.x;
  const float scale = 0.17677669529663687f;
  const size_t base = (size_t)b * KP * (3*Cc);
  for (int i = tid; i < KP*DH; i += 512) {
    int q = i >> 5, d = i & 31;
    Qs[q][d] = qkv[base + (size_t)q*(3*Cc) + h*DH + d] * scale;
  }
  {
    int j = tid >> 2, qc = tid & 3;
    float kf[8], vf[8];
    if (j < KP) {
      const float* sk = qkv + base + (size_t)j*(3*Cc) + Cc   + h*DH + qc*8;
      const float* sv = qkv + base + (size_t)j*(3*Cc) + 2*Cc + h*DH + qc*8;
      #pragma unroll
      for (int e = 0; e < 8; ++e) { kf[e] = sk[e]; vf[e] = sv[e]; }
    } else {
      #pragma unroll
      for (int e = 0; e < 8; ++e) { kf[e] = 0.f; vf[e] = 0.f; }
    }
    ((float4*)Kt[j])[qc*2]   = make_float4(kf[0],kf[1],kf[2],kf[3]);
    ((float4*)Kt[j])[qc*2+1] = make_float4(kf[4],kf[5],kf[6],kf[7]);
    ((float4*)Vt[j])[qc*2]   = make_float4(vf[0],vf[1],vf[2],vf[3]);
    ((float4*)Vt[j])[qc*2+1] = make_float4(vf[4],vf[5],vf[6],vf[7]);
  }
  __syncthreads();
  int w = tid >> 6, lane = tid & 63;
  int d = lane & 31, half = lane >> 5;
  for (int q = w; q < KP; q += 8) {
    float s0 = 0.f, s1 = 0.f;
    #pragma unroll
    for (int c = 0; c < 8; ++c) {
      float4 k0 = ((const float4*)Kt[lane])[c];
      float4 k1 = ((const float4*)Kt[lane+64])[c];
      float4 qv = *(const float4*)&Qs[q][c*4];
      s0 += k0.x*qv.x + k0.y*qv.y + k0.z*qv.z + k0.w*qv.w;
      s1 += k1.x*qv.x + k1.y*qv.y + k1.z*qv.z + k1.w*qv.w;
    }
    if (lane >= KP) s0 = -1e30f;
    if (lane + 64 >= KP) s1 = -1e30f;
    float mx = fmaxf(s0, s1);
    #pragma unroll
    for (int m2 = 32; m2 > 0; m2 >>= 1) mx = fmaxf(mx, __shfl_xor(mx, m2));
    float p0 = (lane < KP)      ? expf(s0 - mx) : 0.f;
    float p1 = (lane + 64 < KP) ? expf(s1 - mx) : 0.f;
    float sm = p0 + p1;
    #pragma unroll
    for (int m2 = 32; m2 > 0; m2 >>= 1) sm += __shfl_xor(sm, m2);
    Ps[w][lane] = p0; Ps[w][lane+64] = p1;
    float pv = 0.f;
    for (int s = 0; s < 64; ++s) {
      int j = half*64 + s;
      pv += Ps[w][j] * Vt[j][d];
    }
    pv += __shfl_xor(pv, 32);
    if (lane < 32) out[((size_t)b*KP + q)*Cc + h*DH + d] = pv / sm;
  }
}

// ---------------- cross-attention: 4096 bf16 keys, online softmax ----------------
__global__ __launch_bounds__(512) void attn_ca(const float* __restrict__ qh,
                                               const bf16* __restrict__ kh,
                                               const bf16* __restrict__ vh,
                                               float* __restrict__ out) {
  __shared__ float Kt[128][36];
  __shared__ float Vt[128][36];
  __shared__ float Qs[KP][DH];
  __shared__ float Ps[8][128];
  int bh = blockIdx.x; int b = bh >> 3, h = bh & 7;
  int tid = threadIdx.x;
  const float scale = 0.17677669529663687f;
  for (int i = tid; i < KP*DH; i += 512) {
    int q = i >> 5, d = i & 31;
    Qs[q][d] = qh[((size_t)b*KP + q)*Cc + h*DH + d] * scale;
  }
  int w = tid >> 6, lane = tid & 63;
  int d = lane & 31, half = lane >> 5;
  float acc[13], mreg[13], lreg[13];
  #pragma unroll
  for (int i = 0; i < 13; ++i) { acc[i] = 0.f; mreg[i] = -1e30f; lreg[i] = 0.f; }
  for (int t0 = 0; t0 < Mm; t0 += 128) {
    __syncthreads();
    {
      int j = tid >> 2, qc = tid & 3;
      size_t rowk = ((size_t)b*Mm + t0 + j)*Cc + h*DH + qc*8;
      uint4 kraw = *(const uint4*)(kh + rowk);
      uint4 vraw = *(const uint4*)(vh + rowk);
      const unsigned short* ks = (const unsigned short*)&kraw;
      const unsigned short* vs = (const unsigned short*)&vraw;
      float kf[8], vf[8];
      #pragma unroll
      for (int e = 0; e < 8; ++e) { kf[e] = bfu2f(ks[e]); vf[e] = bfu2f(vs[e]); }
      ((float4*)Kt[j])[qc*2]   = make_float4(kf[0],kf[1],kf[2],kf[3]);
      ((float4*)Kt[j])[qc*2+1] = make_float4(kf[4],kf[5],kf[6],kf[7]);
      ((float4*)Vt[j])[qc*2]   = make_float4(vf[0],vf[1],vf[2],vf[3]);
      ((float4*)Vt[j])[qc*2+1] = make_float4(vf[4],vf[5],vf[6],vf[7]);
    }
    __syncthreads();
    #pragma unroll
    for (int i = 0; i < 13; ++i) {
      int q = w + 8*i;
      if (q < KP) {
        float s0 = 0.f, s1 = 0.f;
        #pragma unroll
        for (int c = 0; c < 8; ++c) {
          float4 k0 = ((const float4*)Kt[lane])[c];
          float4 k1 = ((const float4*)Kt[lane+64])[c];
          float4 qv = *(const float4*)&Qs[q][c*4];
          s0 += k0.x*qv.x + k0.y*qv.y + k0.z*qv.z + k0.w*qv.w;
          s1 += k1.x*qv.x + k1.y*qv.y + k1.z*qv.z + k1.w*qv.w;
        }
        float mx = fmaxf(s0, s1);
        #pragma unroll
        for (int m2 = 32; m2 > 0; m2 >>= 1) mx = fmaxf(mx, __shfl_xor(mx, m2));
        float newm = fmaxf(mreg[i], mx);
        float p0 = expf(s0 - newm), p1 = expf(s1 - newm);
        float ts = p0 + p1;
        #pragma unroll
        for (int m2 = 32; m2 > 0; m2 >>= 1) ts += __shfl_xor(ts, m2);
        float resc = expf(mreg[i] - newm);
        lreg[i] = lreg[i]*resc + ts;
        mreg[i] = newm;
        Ps[w][lane] = p0; Ps[w][lane+64] = p1;
        float pv = 0.f;
        for (int s = 0; s < 64; ++s) {
          int j = half*64 + s;
          pv += Ps[w][j] * Vt[j][d];
        }
        pv += __shfl_xor(pv, 32);
        acc[i] = acc[i]*resc + pv;
      }
    }
  }
  #pragma unroll
  for (int i = 0; i < 13; ++i) {
    int q = w + 8*i;
    if (q < KP && lane < 32)
      out[((size_t)b*KP + q)*Cc + h*DH + d] = acc[i] / lreg[i];
  }
}

// ---------------- host ----------------
extern "C" void kernel_launch(void* const* d_in, const int* in_sizes, int n_in,
                              void* d_out, int out_size, void* d_ws, size_t ws_size,
                              hipStream_t stream) {
  auto in = [&](int i) { return (const float*)d_in[i]; };
  const float* hs        = in(0);
  const float* mem       = in(1);
  const float* mem_pos   = in(2);
  const float* sub_boxes = in(3);
  const float* obj_boxes = in(4);
  const float* su_w1 = in(5),  *su_b1 = in(6),  *su_w2 = in(7),  *su_b2 = in(8);
  const float* ou_w1 = in(9),  *ou_b1 = in(10), *ou_w2 = in(11), *ou_b2 = in(12);
  const float* pm_w1 = in(13), *pm_b1 = in(14), *pm_w2 = in(15), *pm_b2 = in(16);
  const float* sp_w1 = in(17), *sp_b1 = in(18), *sp_w2 = in(19), *sp_b2 = in(20);
  const float* sa_in_w = in(21),  *sa_in_b = in(22), *sa_out_w = in(23), *sa_out_b = in(24);
  const float* ca_in_w = in(25),  *ca_in_b = in(26), *ca_out_w = in(27), *ca_out_b = in(28);
  const float* l1_w = in(29), *l1_b = in(30), *l2_w = in(31), *l2_b = in(32);
  const float* n1_g = in(33), *n1_b = in(34), *n2_g = in(35), *n2_b = in(36);
  const float* n3_g = in(37), *n3_b = in(38);

  char* wsp = (char*)d_ws;
  auto alloc = [&](size_t bytes) { char* p = wsp; wsp += (bytes + 255) & ~(size_t)255; return p; };
  bf16* khb = (bf16*)alloc((size_t)Bb*Mm*Cc*2);
  bf16* vhb = (bf16*)alloc((size_t)Bb*Mm*Cc*2);
  float* subf    = (float*)alloc((size_t)Bb*Nn*Cc*4);
  float* objf    = (float*)alloc((size_t)Bb*Nn*Cc*4);
  float* sub_emb = (float*)alloc((size_t)Bb*Nn*Cc*4);
  float* obj_emb = (float*)alloc((size_t)Bb*Nn*Cc*4);
  float* embh    = (float*)alloc((size_t)TT*Cc*4);
  float* imp     = (float*)alloc((size_t)Bb*Nn*Nn*4);
  int*   idx     = (int*)  alloc((size_t)Bb*KP*4);
  float* pair_cat= (float*)alloc((size_t)TT*2*Cc*4);
  float* bxc     = (float*)alloc((size_t)TT*8*4);
  float* spb     = (float*)alloc((size_t)TT*Cc*4);
  float* qbuf    = (float*)alloc((size_t)TT*Cc*4);
  float* qkv     = (float*)alloc((size_t)TT*3*Cc*4);
  float* attn_o  = (float*)alloc((size_t)TT*Cc*4);
  float* proj    = (float*)alloc((size_t)TT*Cc*4);
  float* qhb     = (float*)alloc((size_t)TT*Cc*4);
  float* ffnh    = (float*)alloc((size_t)TT*Ff*4);

  auto G = [&](const float* A, const float* A2, const float* Wt, const float* bias,
               void* out, int M, int N, int K, bool relu, bool obf) {
    dim3 g((N + 63)/64, (M + 63)/64), t(256);
    if (obf)       gemm_nt<false,true ><<<g, t, 0, stream>>>(A, A2, Wt, bias, out, M, N, K);
    else if (relu) gemm_nt<true ,false><<<g, t, 0, stream>>>(A, A2, Wt, bias, out, M, N, K);
    else           gemm_nt<false,false><<<g, t, 0, stream>>>(A, A2, Wt, bias, out, M, N, K);
  };

  // front-end
  split_subobj<<<(Bb*Nn*Cc + 255)/256, 256, 0, stream>>>(hs, subf, objf);
  G(subf, nullptr, su_w1, su_b1, embh,    TT, Cc, Cc, true,  false);
  G(embh, nullptr, su_w2, su_b2, sub_emb, TT, Cc, Cc, false, false);
  l2norm_kernel<<<TT, 256, 0, stream>>>(sub_emb);
  G(objf, nullptr, ou_w1, ou_b1, embh,    TT, Cc, Cc, true,  false);
  G(embh, nullptr, ou_w2, ou_b2, obj_emb, TT, Cc, Cc, false, false);
  l2norm_kernel<<<TT, 256, 0, stream>>>(obj_emb);
  importance_kernel<<<Bb*Nn, 128, 0, stream>>>(sub_emb, obj_emb, imp);
  topk_kernel<<<Bb, 256, 0, stream>>>(imp, idx);
  gather_pair<<<TT, 256, 0, stream>>>(subf, objf, idx, pair_cat);
  G(pair_cat, nullptr, pm_w1, pm_b1, embh, TT, Cc, 2*Cc, true,  false);
  G(embh,     nullptr, pm_w2, pm_b2, qbuf, TT, Cc, Cc,   false, false);
  boxes_cat_kernel<<<(TT*8 + 255)/256, 256, 0, stream>>>(sub_boxes, obj_boxes, bxc);
  G(bxc,  nullptr, sp_w1, sp_b1, embh, TT, Cc, 8,  true,  false);
  G(embh, nullptr, sp_w2, sp_b2, spb,  TT, Cc, Cc, false, false);

  // decoder layers
  for (int i = 0; i < Ll; ++i) {
    const float* saw = sa_in_w + (size_t)i*3*Cc*Cc;
    const float* sab = sa_in_b + (size_t)i*3*Cc;
    const float* caw = ca_in_w + (size_t)i*3*Cc*Cc;
    const float* cab = ca_in_b + (size_t)i*3*Cc;

    // self-attention (q_sp = q + sp fused into GEMM)
    G(qbuf, spb, saw, sab, qkv, TT, 3*Cc, Cc, false, false);
    attn_sa<<<Bb*Hh, 512, 0, stream>>>(qkv, attn_o);
    G(attn_o, nullptr, sa_out_w + (size_t)i*Cc*Cc, sa_out_b + (size_t)i*Cc, proj, TT, Cc, Cc, false, false);
    ln_residual<<<TT, 256, 0, stream>>>(qbuf, proj, n1_g + i*Cc, n1_b + i*Cc, qbuf);

    // cross-attention
    G(qbuf, nullptr, caw, cab, qhb, TT, Cc, Cc, false, false);
    G(mem, mem_pos, caw + (size_t)Cc*Cc,   cab + Cc,   khb, Bb*Mm, Cc, Cc, false, true);
    G(mem, nullptr, caw + (size_t)2*Cc*Cc, cab + 2*Cc, vhb, Bb*Mm, Cc, Cc, false, true);
    attn_ca<<<Bb*Hh, 512, 0, stream>>>(qhb, khb, vhb, attn_o);
    G(attn_o, nullptr, ca_out_w + (size_t)i*Cc*Cc, ca_out_b + (size_t)i*Cc, proj, TT, Cc, Cc, false, false);
    ln_residual<<<TT, 256, 0, stream>>>(qbuf, proj, n2_g + i*Cc, n2_b + i*Cc, qbuf);

    // FFN
    G(qbuf, nullptr, l1_w + (size_t)i*Ff*Cc, l1_b + (size_t)i*Ff, ffnh, TT, Ff, Cc, true,  false);
    G(ffnh, nullptr, l2_w + (size_t)i*Cc*Ff, l2_b + (size_t)i*Cc, proj, TT, Cc, Ff, false, false);
    float* qo = (i == Ll-1) ? (float*)d_out : qbuf;
    ln_residual<<<TT, 256, 0, stream>>>(qbuf, proj, n3_g + i*Cc, n3_b + i*Cc, qo);
  }
}

// Round 2
// 8371.981 us; speedup vs baseline: 2.0911x; 2.0911x over previous
//
#include <hip/hip_runtime.h>
#include <hip/hip_bf16.h>

#define Bb 32
#define Nn 100
#define Cc 256
#define Mm 4096
#define Ff 2048
#define Ll 6
#define Hh 8
#define DH 32
#define KP 100
#define TT (Bb*KP)
#define LNEPS 1e-5f
#define NCH 4
#define SUBK 128

typedef __hip_bfloat16 bf16;
typedef __attribute__((ext_vector_type(8))) short short8v;
typedef __attribute__((ext_vector_type(4))) float f32x4;

union FragU { uint2 u2[2]; uint4 u4; short8v s8; };

__device__ __forceinline__ float bfu2f(unsigned short u) {
  union { unsigned u32; float f; } cv; cv.u32 = ((unsigned)u) << 16; return cv.f;
}
__device__ __forceinline__ unsigned short f2bf(float f) {
  union { float f; unsigned u; } c; c.f = f;
  unsigned r = c.u + 0x7FFF + ((c.u >> 16) & 1);
  return (unsigned short)(r >> 16);
}

// ---------------- generic GEMM: out = [A(+A2)] @ W^T + bias ----------------
// OM: 0 = fp32 row-major; 1 = bf16 head-major KV [b][h][4096][32];
//     2 = bf16 head-major Q  [b][h][100][32], pre-scaled by 1/sqrt(32)
template<bool RELU, int OM>
__global__ __launch_bounds__(256) void gemm_nt(
    const float* __restrict__ A, const float* __restrict__ A2,
    const float* __restrict__ Wt, const float* __restrict__ bias,
    void* __restrict__ out, int M, int N, int K)
{
  __shared__ float As[16][68];
  __shared__ float Ws[16][68];
  const int bm = blockIdx.y * 64, bn = blockIdx.x * 64;
  const int tid = threadIdx.x;
  const int kk = tid & 15, rr = tid >> 4;
  const int tx = tid & 15, ty = tid >> 4;
  float acc[4][4] = {};
  for (int k0 = 0; k0 < K; k0 += 16) {
    #pragma unroll
    for (int p = 0; p < 4; ++p) {
      int m = rr + p*16;
      int row = bm + m;
      float av = 0.f, wv = 0.f;
      bool kin = (k0 + kk) < K;
      if (row < M && kin) {
        size_t ai = (size_t)row * K + k0 + kk;
        av = A[ai];
        if (A2) av += A2[ai];
      }
      int wrow = bn + m;
      if (wrow < N && kin) wv = Wt[(size_t)wrow * K + k0 + kk];
      As[kk][m] = av;
      Ws[kk][m] = wv;
    }
    __syncthreads();
    #pragma unroll
    for (int q = 0; q < 16; ++q) {
      float a[4], w[4];
      #pragma unroll
      for (int i = 0; i < 4; ++i) a[i] = As[q][ty*4 + i];
      #pragma unroll
      for (int j = 0; j < 4; ++j) w[j] = Ws[q][tx*4 + j];
      #pragma unroll
      for (int i = 0; i < 4; ++i)
        #pragma unroll
        for (int j = 0; j < 4; ++j) acc[i][j] += a[i] * w[j];
    }
    __syncthreads();
  }
  #pragma unroll
  for (int i = 0; i < 4; ++i) {
    int row = bm + ty*4 + i;
    if (row >= M) continue;
    #pragma unroll
    for (int j = 0; j < 4; ++j) {
      int col = bn + tx*4 + j;
      if (col >= N) continue;
      float v = acc[i][j];
      if (bias) v += bias[col];
      if (RELU) v = v > 0.f ? v : 0.f;
      if (OM == 0) {
        ((float*)out)[(size_t)row*N + col] = v;
      } else if (OM == 1) {
        int bb = row >> 12, m = row & 4095;
        int h = col >> 5, dd = col & 31;
        ((bf16*)out)[(((size_t)bb*Hh + h)*Mm + m)*DH + dd] = __float2bfloat16(v);
      } else {
        int bb = row / KP, qq = row % KP;
        int h = col >> 5, dd = col & 31;
        ((bf16*)out)[(((size_t)bb*Hh + h)*KP + qq)*DH + dd] =
            __float2bfloat16(v * 0.17677669529663687f);
      }
    }
  }
}

// ---------------- small kernels ----------------
__global__ void split_subobj(const float* __restrict__ hs,
                             float* __restrict__ subf, float* __restrict__ objf) {
  int i = blockIdx.x*256 + threadIdx.x;
  if (i >= Bb*Nn*Cc) return;
  int c = i % Cc, n = (i / Cc) % Nn, b = i / (Cc*Nn);
  subf[i] = hs[((size_t)b*2*Nn + 2*n    )*Cc + c];
  objf[i] = hs[((size_t)b*2*Nn + 2*n + 1)*Cc + c];
}

__global__ __launch_bounds__(256) void l2norm_kernel(float* __restrict__ x) {
  int t = blockIdx.x, c = threadIdx.x;
  float v = x[(size_t)t*Cc + c];
  __shared__ float red[256];
  red[c] = v*v; __syncthreads();
  for (int s = 128; s > 0; s >>= 1) { if (c < s) red[c] += red[c+s]; __syncthreads(); }
  float scale = 1.f / (sqrtf(red[0]) + 1e-6f);
  x[(size_t)t*Cc + c] = v * scale;
}

__global__ __launch_bounds__(128) void importance_kernel(const float* __restrict__ se,
                                                         const float* __restrict__ oe,
                                                         float* __restrict__ imp) {
  int b = blockIdx.x / Nn, n = blockIdx.x % Nn;
  int m = threadIdx.x;
  if (m >= Nn) return;
  const float* s = se + ((size_t)b*Nn + n)*Cc;
  const float* o = oe + ((size_t)b*Nn + m)*Cc;
  float acc = 0.f;
  for (int c = 0; c < Cc; ++c) acc += s[c] * o[c];
  imp[((size_t)b*Nn + n)*Nn + m] = acc;
}

__global__ __launch_bounds__(256) void topk_kernel(const float* __restrict__ imp,
                                                   int* __restrict__ idx_out) {
  __shared__ float vals[Nn*Nn];
  __shared__ float rv[256];
  __shared__ int   ri[256];
  int b = blockIdx.x, tid = threadIdx.x;
  for (int i = tid; i < Nn*Nn; i += 256) vals[i] = imp[(size_t)b*Nn*Nn + i];
  __syncthreads();
  for (int k = 0; k < KP; ++k) {
    float bv = -1e30f; int bi = 0x7fffffff;
    for (int i = tid; i < Nn*Nn; i += 256) {
      float v = vals[i];
      if (v > bv || (v == bv && i < bi)) { bv = v; bi = i; }
    }
    rv[tid] = bv; ri[tid] = bi; __syncthreads();
    for (int s = 128; s > 0; s >>= 1) {
      if (tid < s) {
        float v2 = rv[tid+s]; int i2 = ri[tid+s];
        if (v2 > rv[tid] || (v2 == rv[tid] && i2 < ri[tid])) { rv[tid] = v2; ri[tid] = i2; }
      }
      __syncthreads();
    }
    if (tid == 0) { idx_out[b*KP + k] = ri[0]; vals[ri[0]] = -1e30f; }
    __syncthreads();
  }
}

__global__ __launch_bounds__(256) void gather_pair(const float* __restrict__ subf,
                                                   const float* __restrict__ objf,
                                                   const int* __restrict__ idx,
                                                   float* __restrict__ pc) {
  int bk = blockIdx.x;
  int b = bk / KP;
  int id = idx[bk];
  int spos = id / Nn, opos = id % Nn;
  const float* s = subf + ((size_t)b*Nn + spos)*Cc;
  const float* o = objf + ((size_t)b*Nn + opos)*Cc;
  float* dst = pc + (size_t)bk * (2*Cc);
  for (int c = threadIdx.x; c < Cc; c += 256) { dst[c] = s[c]; dst[Cc + c] = o[c]; }
}

__global__ void boxes_cat_kernel(const float* __restrict__ sb, const float* __restrict__ ob,
                                 float* __restrict__ out) {
  int i = blockIdx.x*256 + threadIdx.x;
  if (i >= TT*8) return;
  int c = i & 7, bk = i >> 3;
  out[i] = (c < 4) ? sb[bk*4 + c] : ob[bk*4 + (c - 4)];
}

__global__ __launch_bounds__(256) void ln_residual(const float* __restrict__ qin,
                                                   const float* __restrict__ delta,
                                                   const float* __restrict__ g,
                                                   const float* __restrict__ bta,
                                                   float* __restrict__ qout) {
  int t = blockIdx.x, c = threadIdx.x;
  float x = qin[(size_t)t*Cc + c] + delta[(size_t)t*Cc + c];
  __shared__ float red[256];
  red[c] = x; __syncthreads();
  for (int s = 128; s > 0; s >>= 1) { if (c < s) red[c] += red[c+s]; __syncthreads(); }
  float mean = red[0] * (1.f/Cc);
  __syncthreads();
  float d = x - mean;
  red[c] = d*d; __syncthreads();
  for (int s = 128; s > 0; s >>= 1) { if (c < s) red[c] += red[c+s]; __syncthreads(); }
  float var = red[0] * (1.f/Cc);
  qout[(size_t)t*Cc + c] = d * rsqrtf(var + LNEPS) * g[c] + bta[c];
}

// ---------------- self-attention: 100 keys, one tile ----------------
__global__ __launch_bounds__(512) void attn_sa(const float* __restrict__ qkv,
                                               float* __restrict__ out) {
  __shared__ float Kt[128][36];
  __shared__ float Vt[128][36];
  __shared__ float Qs[KP][DH];
  __shared__ float Ps[8][128];
  int bh = blockIdx.x; int b = bh >> 3, h = bh & 7;
  int tid = threadIdx.x;
  const float scale = 0.17677669529663687f;
  const size_t base = (size_t)b * KP * (3*Cc);
  for (int i = tid; i < KP*DH; i += 512) {
    int q = i >> 5, d = i & 31;
    Qs[q][d] = qkv[base + (size_t)q*(3*Cc) + h*DH + d] * scale;
  }
  {
    int j = tid >> 2, qc = tid & 3;
    float kf[8], vf[8];
    if (j < KP) {
      const float* sk = qkv + base + (size_t)j*(3*Cc) + Cc   + h*DH + qc*8;
      const float* sv = qkv + base + (size_t)j*(3*Cc) + 2*Cc + h*DH + qc*8;
      #pragma unroll
      for (int e = 0; e < 8; ++e) { kf[e] = sk[e]; vf[e] = sv[e]; }
    } else {
      #pragma unroll
      for (int e = 0; e < 8; ++e) { kf[e] = 0.f; vf[e] = 0.f; }
    }
    ((float4*)Kt[j])[qc*2]   = make_float4(kf[0],kf[1],kf[2],kf[3]);
    ((float4*)Kt[j])[qc*2+1] = make_float4(kf[4],kf[5],kf[6],kf[7]);
    ((float4*)Vt[j])[qc*2]   = make_float4(vf[0],vf[1],vf[2],vf[3]);
    ((float4*)Vt[j])[qc*2+1] = make_float4(vf[4],vf[5],vf[6],vf[7]);
  }
  __syncthreads();
  int w = tid >> 6, lane = tid & 63;
  int d = lane & 31, half = lane >> 5;
  for (int q = w; q < KP; q += 8) {
    float s0 = 0.f, s1 = 0.f;
    #pragma unroll
    for (int c = 0; c < 8; ++c) {
      float4 k0 = ((const float4*)Kt[lane])[c];
      float4 k1 = ((const float4*)Kt[lane+64])[c];
      float4 qv = *(const float4*)&Qs[q][c*4];
      s0 += k0.x*qv.x + k0.y*qv.y + k0.z*qv.z + k0.w*qv.w;
      s1 += k1.x*qv.x + k1.y*qv.y + k1.z*qv.z + k1.w*qv.w;
    }
    if (lane >= KP) s0 = -1e30f;
    if (lane + 64 >= KP) s1 = -1e30f;
    float mx = fmaxf(s0, s1);
    #pragma unroll
    for (int m2 = 32; m2 > 0; m2 >>= 1) mx = fmaxf(mx, __shfl_xor(mx, m2));
    float p0 = (lane < KP)      ? expf(s0 - mx) : 0.f;
    float p1 = (lane + 64 < KP) ? expf(s1 - mx) : 0.f;
    float sm = p0 + p1;
    #pragma unroll
    for (int m2 = 32; m2 > 0; m2 >>= 1) sm += __shfl_xor(sm, m2);
    Ps[w][lane] = p0; Ps[w][lane+64] = p1;
    float pv = 0.f;
    for (int s = 0; s < 64; ++s) {
      int j = half*64 + s;
      pv += Ps[w][j] * Vt[j][d];
    }
    pv += __shfl_xor(pv, 32);
    if (lane < 32) out[((size_t)b*KP + q)*Cc + h*DH + d] = pv / sm;
  }
}

// ---------------- cross-attention: MFMA flash-decode ----------------
// grid: (bh * NCH) blocks, 256 thr (4 waves). chunk = Mm/NCH keys, staged 128 at a time.
// Per wave: q-tiles qt=w and qt=w+4 (q padded to 128).
// S^T = K·Q^T via mfma (lane holds one q col); P via LDS [q][k]; O^T = V^T·P^T.
__global__ __launch_bounds__(256) void attn_ca_mfma(
    const bf16* __restrict__ qhH,   // [bh][100][32] pre-scaled
    const bf16* __restrict__ khH,   // [bh][4096][32]
    const bf16* __restrict__ vhH,   // [bh][4096][32]
    bf16* __restrict__ part,        // [bh][NCH][100][32]
    float2* __restrict__ ml)        // [bh][NCH][100]
{
  __shared__ unsigned short Qs[128][36];
  __shared__ unsigned short Ks[128][36];
  __shared__ unsigned short Vs[32][140];
  __shared__ unsigned short Ps[128][140];
  const int bx = blockIdx.x;
  const int bh = bx >> 2, ch = bx & 3;
  const int tid = threadIdx.x;
  const int w = tid >> 6, lane = tid & 63;
  const int lr = lane & 15, lg = lane >> 4;
  const int k0base = ch * (Mm / NCH);

  // stage Q (rows >= 100 zeroed)
  for (int i = tid; i < 128*4; i += 256) {
    int q = i >> 2, c = i & 3;
    uint4 v = make_uint4(0u,0u,0u,0u);
    if (q < KP) v = *(const uint4*)(qhH + ((size_t)bh*KP + q)*DH + c*8);
    *(uint2*)&Qs[q][c*8]     = make_uint2(v.x, v.y);
    *(uint2*)&Qs[q][c*8 + 4] = make_uint2(v.z, v.w);
  }
  __syncthreads();
  const int qt0 = w, qt1 = w + 4;
  FragU qf[2];
  qf[0].u2[0] = *(const uint2*)&Qs[qt0*16 + lr][lg*8];
  qf[0].u2[1] = *(const uint2*)&Qs[qt0*16 + lr][lg*8 + 4];
  qf[1].u2[0] = *(const uint2*)&Qs[qt1*16 + lr][lg*8];
  qf[1].u2[1] = *(const uint2*)&Qs[qt1*16 + lr][lg*8 + 4];

  f32x4 acc[2][2] = {};             // [qtile][dtile], C-layout: row=d, col=q
  float mreg[2] = {-1e30f, -1e30f};
  float lreg[2] = {0.f, 0.f};

  for (int sc = 0; sc < (Mm/NCH)/SUBK; ++sc) {
    const int k0 = k0base + sc*SUBK;
    __syncthreads();   // prior compute done before K/V/P overwrite
    // stage K rows (128 x 32 bf16)
    #pragma unroll
    for (int i = tid; i < 128*4; i += 256) {
      int m = i >> 2, c = i & 3;
      uint4 v = *(const uint4*)(khH + ((size_t)bh*Mm + k0 + m)*DH + c*8);
      *(uint2*)&Ks[m][c*8]     = make_uint2(v.x, v.y);
      *(uint2*)&Ks[m][c*8 + 4] = make_uint2(v.z, v.w);
    }
    // stage V transposed: Vs[d][k]
    {
      int p2 = tid & 63, c = tid >> 6;
      uint4 v0 = *(const uint4*)(vhH + ((size_t)bh*Mm + k0 + 2*p2    )*DH + c*8);
      uint4 v1 = *(const uint4*)(vhH + ((size_t)bh*Mm + k0 + 2*p2 + 1)*DH + c*8);
      const unsigned short* a0 = (const unsigned short*)&v0;
      const unsigned short* a1 = (const unsigned short*)&v1;
      #pragma unroll
      for (int e = 0; e < 8; ++e) {
        int d = c*8 + e;
        *(unsigned int*)&Vs[d][2*p2] = (unsigned)a0[e] | ((unsigned)a1[e] << 16);
      }
    }
    __syncthreads();

    // scores: S^T[key][q] = K · Q^T
    f32x4 sv[2][8];
    #pragma unroll
    for (int kt = 0; kt < 8; ++kt) {
      FragU kf;
      kf.u2[0] = *(const uint2*)&Ks[kt*16 + lr][lg*8];
      kf.u2[1] = *(const uint2*)&Ks[kt*16 + lr][lg*8 + 4];
      f32x4 z = {0.f, 0.f, 0.f, 0.f};
      sv[0][kt] = __builtin_amdgcn_mfma_f32_16x16x32_bf16(kf.s8, qf[0].s8, z, 0, 0, 0);
      sv[1][kt] = __builtin_amdgcn_mfma_f32_16x16x32_bf16(kf.s8, qf[1].s8, z, 0, 0, 0);
    }

    // online softmax per q-tile; write P (bf16) to LDS [q][k]
    #pragma unroll
    for (int j = 0; j < 2; ++j) {
      int qrow = (j ? qt1 : qt0)*16 + lr;
      float mx = -1e30f;
      #pragma unroll
      for (int kt = 0; kt < 8; ++kt)
        mx = fmaxf(mx, fmaxf(fmaxf(sv[j][kt][0], sv[j][kt][1]),
                             fmaxf(sv[j][kt][2], sv[j][kt][3])));
      mx = fmaxf(mx, __shfl_xor(mx, 16));
      mx = fmaxf(mx, __shfl_xor(mx, 32));
      float newm = fmaxf(mreg[j], mx);
      float resc = __expf(mreg[j] - newm);
      mreg[j] = newm;
      float psum = 0.f;
      #pragma unroll
      for (int kt = 0; kt < 8; ++kt) {
        float p0 = __expf(sv[j][kt][0] - newm);
        float p1 = __expf(sv[j][kt][1] - newm);
        float p2 = __expf(sv[j][kt][2] - newm);
        float p3 = __expf(sv[j][kt][3] - newm);
        psum += (p0 + p1) + (p2 + p3);
        unsigned lo = (unsigned)f2bf(p0) | ((unsigned)f2bf(p1) << 16);
        unsigned hi = (unsigned)f2bf(p2) | ((unsigned)f2bf(p3) << 16);
        *(uint2*)&Ps[qrow][kt*16 + lg*4] = make_uint2(lo, hi);
      }
      psum += __shfl_xor(psum, 16);
      psum += __shfl_xor(psum, 32);
      lreg[j] = lreg[j]*resc + psum;
      #pragma unroll
      for (int dt = 0; dt < 2; ++dt)
        #pragma unroll
        for (int r = 0; r < 4; ++r) acc[j][dt][r] *= resc;
    }

    // PV: O^T[d][q] += V^T · P^T  (K-dim = 128 keys, 4 mfma steps)
    #pragma unroll
    for (int ks = 0; ks < 4; ++ks) {
      FragU vf[2], pf[2];
      #pragma unroll
      for (int dt = 0; dt < 2; ++dt) {
        vf[dt].u2[0] = *(const uint2*)&Vs[dt*16 + lr][ks*32 + lg*8];
        vf[dt].u2[1] = *(const uint2*)&Vs[dt*16 + lr][ks*32 + lg*8 + 4];
      }
      #pragma unroll
      for (int j = 0; j < 2; ++j) {
        int qrow = (j ? qt1 : qt0)*16 + lr;
        pf[j].u2[0] = *(const uint2*)&Ps[qrow][ks*32 + lg*8];
        pf[j].u2[1] = *(const uint2*)&Ps[qrow][ks*32 + lg*8 + 4];
      }
      #pragma unroll
      for (int j = 0; j < 2; ++j)
        #pragma unroll
        for (int dt = 0; dt < 2; ++dt)
          acc[j][dt] = __builtin_amdgcn_mfma_f32_16x16x32_bf16(vf[dt].s8, pf[j].s8,
                                                               acc[j][dt], 0, 0, 0);
    }
  }

  // write partials
  #pragma unroll
  for (int j = 0; j < 2; ++j) {
    int q = (j ? qt1 : qt0)*16 + lr;
    if (q < KP) {
      if (lg == 0) ml[((size_t)bh*NCH + ch)*KP + q] = make_float2(mreg[j], lreg[j]);
      #pragma unroll
      for (int dt = 0; dt < 2; ++dt)
        #pragma unroll
        for (int r = 0; r < 4; ++r) {
          int d = dt*16 + lg*4 + r;
          part[(((size_t)bh*NCH + ch)*KP + q)*DH + d] = __float2bfloat16(acc[j][dt][r]);
        }
    }
  }
}

__global__ __launch_bounds__(256) void ca_combine(const bf16* __restrict__ part,
                                                  const float2* __restrict__ ml,
                                                  float* __restrict__ attn_o) {
  int idx = blockIdx.x*256 + threadIdx.x;
  if (idx >= Bb*Hh*KP*DH) return;
  int d = idx & 31;
  int q = (idx >> 5) % KP;
  int bh = idx / (KP*DH);
  int b = bh >> 3, h = bh & 7;
  float m0 = -1e30f;
  float2 mls[NCH];
  #pragma unroll
  for (int c = 0; c < NCH; ++c) {
    mls[c] = ml[((size_t)bh*NCH + c)*KP + q];
    m0 = fmaxf(m0, mls[c].x);
  }
  float L = 0.f, O = 0.f;
  #pragma unroll
  for (int c = 0; c < NCH; ++c) {
    float wgt = __expf(mls[c].x - m0);
    L += mls[c].y * wgt;
    O += __bfloat162float(part[(((size_t)bh*NCH + c)*KP + q)*DH + d]) * wgt;
  }
  attn_o[((size_t)b*KP + q)*Cc + h*DH + d] = O / L;
}

// ---------------- host ----------------
extern "C" void kernel_launch(void* const* d_in, const int* in_sizes, int n_in,
                              void* d_out, int out_size, void* d_ws, size_t ws_size,
                              hipStream_t stream) {
  auto in = [&](int i) { return (const float*)d_in[i]; };
  const float* hs        = in(0);
  const float* mem       = in(1);
  const float* mem_pos   = in(2);
  const float* sub_boxes = in(3);
  const float* obj_boxes = in(4);
  const float* su_w1 = in(5),  *su_b1 = in(6),  *su_w2 = in(7),  *su_b2 = in(8);
  const float* ou_w1 = in(9),  *ou_b1 = in(10), *ou_w2 = in(11), *ou_b2 = in(12);
  const float* pm_w1 = in(13), *pm_b1 = in(14), *pm_w2 = in(15), *pm_b2 = in(16);
  const float* sp_w1 = in(17), *sp_b1 = in(18), *sp_w2 = in(19), *sp_b2 = in(20);
  const float* sa_in_w = in(21),  *sa_in_b = in(22), *sa_out_w = in(23), *sa_out_b = in(24);
  const float* ca_in_w = in(25),  *ca_in_b = in(26), *ca_out_w = in(27), *ca_out_b = in(28);
  const float* l1_w = in(29), *l1_b = in(30), *l2_w = in(31), *l2_b = in(32);
  const float* n1_g = in(33), *n1_b = in(34), *n2_g = in(35), *n2_b = in(36);
  const float* n3_g = in(37), *n3_b = in(38);

  char* wsp = (char*)d_ws;
  auto alloc = [&](size_t bytes) { char* p = wsp; wsp += (bytes + 255) & ~(size_t)255; return p; };
  bf16* khH = (bf16*)alloc((size_t)Bb*Mm*Cc*2);
  bf16* vhH = (bf16*)alloc((size_t)Bb*Mm*Cc*2);
  bf16* qhH = (bf16*)alloc((size_t)TT*Cc*2);
  bf16* part = (bf16*)alloc((size_t)Bb*Hh*NCH*KP*DH*2);
  float2* mlbuf = (float2*)alloc((size_t)Bb*Hh*NCH*KP*8);
  float* subf    = (float*)alloc((size_t)Bb*Nn*Cc*4);
  float* objf    = (float*)alloc((size_t)Bb*Nn*Cc*4);
  float* sub_emb = (float*)alloc((size_t)Bb*Nn*Cc*4);
  float* obj_emb = (float*)alloc((size_t)Bb*Nn*Cc*4);
  float* embh    = (float*)alloc((size_t)TT*Cc*4);
  float* imp     = (float*)alloc((size_t)Bb*Nn*Nn*4);
  int*   idx     = (int*)  alloc((size_t)Bb*KP*4);
  float* pair_cat= (float*)alloc((size_t)TT*2*Cc*4);
  float* bxc     = (float*)alloc((size_t)TT*8*4);
  float* spb     = (float*)alloc((size_t)TT*Cc*4);
  float* qbuf    = (float*)alloc((size_t)TT*Cc*4);
  float* qkv     = (float*)alloc((size_t)TT*3*Cc*4);
  float* attn_o  = (float*)alloc((size_t)TT*Cc*4);
  float* proj    = (float*)alloc((size_t)TT*Cc*4);
  float* ffnh    = (float*)alloc((size_t)TT*Ff*4);

  auto G = [&](const float* A, const float* A2, const float* Wt, const float* bias,
               void* out, int M, int N, int K, bool relu, int om) {
    dim3 g((N + 63)/64, (M + 63)/64), t(256);
    if (om == 1)      gemm_nt<false,1><<<g, t, 0, stream>>>(A, A2, Wt, bias, out, M, N, K);
    else if (om == 2) gemm_nt<false,2><<<g, t, 0, stream>>>(A, A2, Wt, bias, out, M, N, K);
    else if (relu)    gemm_nt<true ,0><<<g, t, 0, stream>>>(A, A2, Wt, bias, out, M, N, K);
    else              gemm_nt<false,0><<<g, t, 0, stream>>>(A, A2, Wt, bias, out, M, N, K);
  };

  // front-end
  split_subobj<<<(Bb*Nn*Cc + 255)/256, 256, 0, stream>>>(hs, subf, objf);
  G(subf, nullptr, su_w1, su_b1, embh,    TT, Cc, Cc, true,  0);
  G(embh, nullptr, su_w2, su_b2, sub_emb, TT, Cc, Cc, false, 0);
  l2norm_kernel<<<TT, 256, 0, stream>>>(sub_emb);
  G(objf, nullptr, ou_w1, ou_b1, embh,    TT, Cc, Cc, true,  0);
  G(embh, nullptr, ou_w2, ou_b2, obj_emb, TT, Cc, Cc, false, 0);
  l2norm_kernel<<<TT, 256, 0, stream>>>(obj_emb);
  importance_kernel<<<Bb*Nn, 128, 0, stream>>>(sub_emb, obj_emb, imp);
  topk_kernel<<<Bb, 256, 0, stream>>>(imp, idx);
  gather_pair<<<TT, 256, 0, stream>>>(subf, objf, idx, pair_cat);
  G(pair_cat, nullptr, pm_w1, pm_b1, embh, TT, Cc, 2*Cc, true,  0);
  G(embh,     nullptr, pm_w2, pm_b2, qbuf, TT, Cc, Cc,   false, 0);
  boxes_cat_kernel<<<(TT*8 + 255)/256, 256, 0, stream>>>(sub_boxes, obj_boxes, bxc);
  G(bxc,  nullptr, sp_w1, sp_b1, embh, TT, Cc, 8,  true,  0);
  G(embh, nullptr, sp_w2, sp_b2, spb,  TT, Cc, Cc, false, 0);

  // decoder layers
  for (int i = 0; i < Ll; ++i) {
    const float* saw = sa_in_w + (size_t)i*3*Cc*Cc;
    const float* sab = sa_in_b + (size_t)i*3*Cc;
    const float* caw = ca_in_w + (size_t)i*3*Cc*Cc;
    const float* cab = ca_in_b + (size_t)i*3*Cc;

    // self-attention (q_sp = q + sp fused into GEMM)
    G(qbuf, spb, saw, sab, qkv, TT, 3*Cc, Cc, false, 0);
    attn_sa<<<Bb*Hh, 512, 0, stream>>>(qkv, attn_o);
    G(attn_o, nullptr, sa_out_w + (size_t)i*Cc*Cc, sa_out_b + (size_t)i*Cc, proj, TT, Cc, Cc, false, 0);
    ln_residual<<<TT, 256, 0, stream>>>(qbuf, proj, n1_g + i*Cc, n1_b + i*Cc, qbuf);

    // cross-attention (head-major projections + MFMA flash-decode)
    G(qbuf, nullptr, caw, cab, qhH, TT, Cc, Cc, false, 2);
    G(mem, mem_pos, caw + (size_t)Cc*Cc,   cab + Cc,   khH, Bb*Mm, Cc, Cc, false, 1);
    G(mem, nullptr, caw + (size_t)2*Cc*Cc, cab + 2*Cc, vhH, Bb*Mm, Cc, Cc, false, 1);
    attn_ca_mfma<<<Bb*Hh*NCH, 256, 0, stream>>>(qhH, khH, vhH, part, mlbuf);
    ca_combine<<<(Bb*Hh*KP*DH + 255)/256, 256, 0, stream>>>(part, mlbuf, attn_o);
    G(attn_o, nullptr, ca_out_w + (size_t)i*Cc*Cc, ca_out_b + (size_t)i*Cc, proj, TT, Cc, Cc, false, 0);
    ln_residual<<<TT, 256, 0, stream>>>(qbuf, proj, n2_g + i*Cc, n2_b + i*Cc, qbuf);

    // FFN
    G(qbuf, nullptr, l1_w + (size_t)i*Ff*Cc, l1_b + (size_t)i*Ff, ffnh, TT, Ff, Cc, true,  0);
    G(ffnh, nullptr, l2_w + (size_t)i*Cc*Ff, l2_b + (size_t)i*Cc, proj, TT, Cc, Ff, false, 0);
    float* qo = (i == Ll-1) ? (float*)d_out : qbuf;
    ln_residual<<<TT, 256, 0, stream>>>(qbuf, proj, n3_g + i*Cc, n3_b + i*Cc, qo);
  }
}

// Round 3
// 3116.651 us; speedup vs baseline: 5.6170x; 2.6862x over previous
//
#include <hip/hip_runtime.h>
#include <hip/hip_bf16.h>

#define Bb 32
#define Nn 100
#define Cc 256
#define Mm 4096
#define Ff 2048
#define Ll 6
#define Hh 8
#define DH 32
#define KP 100
#define TT (Bb*KP)
#define LNEPS 1e-5f
#define NCH 4
#define SUBK 128

typedef __hip_bfloat16 bf16;
typedef unsigned short ushort_t;
typedef __attribute__((ext_vector_type(8))) short short8v;
typedef __attribute__((ext_vector_type(4))) float f32x4;

union FragU { uint2 u2[2]; uint4 u4; short8v s8; };

__device__ __forceinline__ float bfu2f(unsigned short u) {
  union { unsigned u32; float f; } cv; cv.u32 = ((unsigned)u) << 16; return cv.f;
}
__device__ __forceinline__ unsigned short f2bf(float f) {
  union { float f; unsigned u; } c; c.f = f;
  unsigned r = c.u + 0x7FFF + ((c.u >> 16) & 1);
  return (unsigned short)(r >> 16);
}
__device__ __forceinline__ unsigned pack2(float a, float b) {
  return (unsigned)f2bf(a) | ((unsigned)f2bf(b) << 16);
}

// ---------------- bf16 MFMA GEMM: out = [A(+A2)] @ W^T + bias ----------------
// A: [M,K] (fp32 if AT==0, bf16 if AT==1) row-major. W: [N,K] bf16 row-major.
// M%128==0, N%128==0, K%64==0 required.
// OM: 0 fp32 row-major; 1 bf16 row-major; 2 bf16 head-major KV [b][h][4096][32];
//     3 bf16 head-major Q [b][h][100][32] scaled by 1/sqrt(32).
template<int AT, bool RELU, int OM>
__global__ __launch_bounds__(256) void gemm_mfma(
    const void* __restrict__ Av, const float* __restrict__ A2,
    const bf16* __restrict__ W, const float* __restrict__ bias,
    void* __restrict__ out, int M, int N, int K)
{
  __shared__ ushort_t As[128][72];
  __shared__ ushort_t Bs[128][72];
  const int mt = M >> 7, nt = N >> 7;
  const int nwg = mt * nt;
  // bijective chunked XCD swizzle: each XCD gets a contiguous wgid range so
  // consecutive wgids (which share an A-panel when nt small) hit the same L2.
  const int g = blockIdx.x;
  const int xcd = g & 7, lid = g >> 3;
  const int q8 = nwg >> 3, r8 = nwg & 7;
  const int wgid = (xcd < r8 ? xcd*(q8+1) : r8*(q8+1) + (xcd - r8)*q8) + lid;
  const int ntile = wgid % nt, mtile = wgid / nt;
  const int bm = mtile << 7, bn = ntile << 7;
  const int tid = threadIdx.x;
  const int w = tid >> 6, lane = tid & 63;
  const int lr = lane & 15, lg = lane >> 4;
  const int wm = w >> 1, wn = w & 1;
  const float* Af = (const float*)Av;
  const bf16*  Ab = (const bf16*)Av;

  f32x4 acc[4][4] = {};

  for (int k0 = 0; k0 < K; k0 += 64) {
    __syncthreads();
    #pragma unroll
    for (int i = 0; i < 4; ++i) {
      int linear = i*256 + tid;
      int row = linear >> 3, c8 = linear & 7;
      uint4 packed;
      if (AT == 0) {
        const float* ap = Af + (size_t)(bm+row)*K + k0 + c8*8;
        float4 f0 = *(const float4*)ap;
        float4 f1 = *(const float4*)(ap+4);
        if (A2) {
          const float* ap2 = A2 + (size_t)(bm+row)*K + k0 + c8*8;
          float4 g0 = *(const float4*)ap2;
          float4 g1 = *(const float4*)(ap2+4);
          f0.x += g0.x; f0.y += g0.y; f0.z += g0.z; f0.w += g0.w;
          f1.x += g1.x; f1.y += g1.y; f1.z += g1.z; f1.w += g1.w;
        }
        packed.x = pack2(f0.x, f0.y); packed.y = pack2(f0.z, f0.w);
        packed.z = pack2(f1.x, f1.y); packed.w = pack2(f1.z, f1.w);
      } else {
        packed = *(const uint4*)(Ab + (size_t)(bm+row)*K + k0 + c8*8);
      }
      *(uint4*)&As[row][c8*8] = packed;
      uint4 wb = *(const uint4*)(W + (size_t)(bn+row)*K + k0 + c8*8);
      *(uint4*)&Bs[row][c8*8] = wb;
    }
    __syncthreads();
    #pragma unroll
    for (int kk = 0; kk < 64; kk += 32) {
      FragU a[4];
      #pragma unroll
      for (int mi = 0; mi < 4; ++mi)
        a[mi].u4 = *(const uint4*)&As[wm*64 + mi*16 + lr][kk + lg*8];
      #pragma unroll
      for (int ni = 0; ni < 4; ++ni) {
        FragU bfr;
        bfr.u4 = *(const uint4*)&Bs[wn*64 + ni*16 + lr][kk + lg*8];
        #pragma unroll
        for (int mi = 0; mi < 4; ++mi)
          acc[mi][ni] = __builtin_amdgcn_mfma_f32_16x16x32_bf16(a[mi].s8, bfr.s8,
                                                                acc[mi][ni], 0, 0, 0);
      }
    }
  }

  #pragma unroll
  for (int ni = 0; ni < 4; ++ni) {
    int col = bn + wn*64 + ni*16 + lr;
    float bv = bias ? bias[col] : 0.f;
    #pragma unroll
    for (int mi = 0; mi < 4; ++mi) {
      #pragma unroll
      for (int r = 0; r < 4; ++r) {
        int m = bm + wm*64 + mi*16 + lg*4 + r;
        float v = acc[mi][ni][r] + bv;
        if (RELU) v = fmaxf(v, 0.f);
        if (OM == 0) {
          ((float*)out)[(size_t)m*N + col] = v;
        } else if (OM == 1) {
          ((bf16*)out)[(size_t)m*N + col] = __float2bfloat16(v);
        } else if (OM == 2) {
          int bb = m >> 12, mm = m & 4095;
          int h = col >> 5, dd = col & 31;
          ((bf16*)out)[(((size_t)bb*Hh + h)*Mm + mm)*DH + dd] = __float2bfloat16(v);
        } else {
          int bb = m / KP, qq = m % KP;
          int h = col >> 5, dd = col & 31;
          ((bf16*)out)[(((size_t)bb*Hh + h)*KP + qq)*DH + dd] =
              __float2bfloat16(v * 0.17677669529663687f);
        }
      }
    }
  }
}

// fp32 -> bf16 weight conversion (n % 4 == 0)
__global__ void cvt_f2b(const float* __restrict__ in, bf16* __restrict__ out, int n4) {
  int i = blockIdx.x*256 + threadIdx.x;
  if (i >= n4) return;
  float4 f = *(const float4*)(in + (size_t)i*4);
  uint2 p; p.x = pack2(f.x, f.y); p.y = pack2(f.z, f.w);
  *(uint2*)(out + (size_t)i*4) = p;
}

// ---------------- fp32 GEMM (front-end only) ----------------
template<bool RELU>
__global__ __launch_bounds__(256) void gemm_nt(
    const float* __restrict__ A, const float* __restrict__ Wt,
    const float* __restrict__ bias, float* __restrict__ out, int M, int N, int K)
{
  __shared__ float As[16][68];
  __shared__ float Ws[16][68];
  const int bm = blockIdx.y * 64, bn = blockIdx.x * 64;
  const int tid = threadIdx.x;
  const int kk = tid & 15, rr = tid >> 4;
  const int tx = tid & 15, ty = tid >> 4;
  float acc[4][4] = {};
  for (int k0 = 0; k0 < K; k0 += 16) {
    #pragma unroll
    for (int p = 0; p < 4; ++p) {
      int m = rr + p*16;
      int row = bm + m;
      float av = 0.f, wv = 0.f;
      bool kin = (k0 + kk) < K;
      if (row < M && kin) av = A[(size_t)row * K + k0 + kk];
      int wrow = bn + m;
      if (wrow < N && kin) wv = Wt[(size_t)wrow * K + k0 + kk];
      As[kk][m] = av;
      Ws[kk][m] = wv;
    }
    __syncthreads();
    #pragma unroll
    for (int q = 0; q < 16; ++q) {
      float a[4], w[4];
      #pragma unroll
      for (int i = 0; i < 4; ++i) a[i] = As[q][ty*4 + i];
      #pragma unroll
      for (int j = 0; j < 4; ++j) w[j] = Ws[q][tx*4 + j];
      #pragma unroll
      for (int i = 0; i < 4; ++i)
        #pragma unroll
        for (int j = 0; j < 4; ++j) acc[i][j] += a[i] * w[j];
    }
    __syncthreads();
  }
  #pragma unroll
  for (int i = 0; i < 4; ++i) {
    int row = bm + ty*4 + i;
    if (row >= M) continue;
    #pragma unroll
    for (int j = 0; j < 4; ++j) {
      int col = bn + tx*4 + j;
      if (col >= N) continue;
      float v = acc[i][j];
      if (bias) v += bias[col];
      if (RELU) v = v > 0.f ? v : 0.f;
      out[(size_t)row*N + col] = v;
    }
  }
}

// ---------------- small kernels ----------------
__global__ void split_subobj(const float* __restrict__ hs,
                             float* __restrict__ subf, float* __restrict__ objf) {
  int i = blockIdx.x*256 + threadIdx.x;
  if (i >= Bb*Nn*Cc) return;
  int c = i % Cc, n = (i / Cc) % Nn, b = i / (Cc*Nn);
  subf[i] = hs[((size_t)b*2*Nn + 2*n    )*Cc + c];
  objf[i] = hs[((size_t)b*2*Nn + 2*n + 1)*Cc + c];
}

__global__ __launch_bounds__(256) void l2norm_kernel(float* __restrict__ x) {
  int t = blockIdx.x, c = threadIdx.x;
  float v = x[(size_t)t*Cc + c];
  __shared__ float red[256];
  red[c] = v*v; __syncthreads();
  for (int s = 128; s > 0; s >>= 1) { if (c < s) red[c] += red[c+s]; __syncthreads(); }
  float scale = 1.f / (sqrtf(red[0]) + 1e-6f);
  x[(size_t)t*Cc + c] = v * scale;
}

__global__ __launch_bounds__(128) void importance_kernel(const float* __restrict__ se,
                                                         const float* __restrict__ oe,
                                                         float* __restrict__ imp) {
  int b = blockIdx.x / Nn, n = blockIdx.x % Nn;
  int m = threadIdx.x;
  if (m >= Nn) return;
  const float* s = se + ((size_t)b*Nn + n)*Cc;
  const float* o = oe + ((size_t)b*Nn + m)*Cc;
  float acc = 0.f;
  for (int c = 0; c < Cc; ++c) acc += s[c] * o[c];
  imp[((size_t)b*Nn + n)*Nn + m] = acc;
}

__global__ __launch_bounds__(256) void topk_kernel(const float* __restrict__ imp,
                                                   int* __restrict__ idx_out) {
  __shared__ float vals[Nn*Nn];
  __shared__ float rv[256];
  __shared__ int   ri[256];
  int b = blockIdx.x, tid = threadIdx.x;
  for (int i = tid; i < Nn*Nn; i += 256) vals[i] = imp[(size_t)b*Nn*Nn + i];
  __syncthreads();
  for (int k = 0; k < KP; ++k) {
    float bv = -1e30f; int bi = 0x7fffffff;
    for (int i = tid; i < Nn*Nn; i += 256) {
      float v = vals[i];
      if (v > bv || (v == bv && i < bi)) { bv = v; bi = i; }
    }
    rv[tid] = bv; ri[tid] = bi; __syncthreads();
    for (int s = 128; s > 0; s >>= 1) {
      if (tid < s) {
        float v2 = rv[tid+s]; int i2 = ri[tid+s];
        if (v2 > rv[tid] || (v2 == rv[tid] && i2 < ri[tid])) { rv[tid] = v2; ri[tid] = i2; }
      }
      __syncthreads();
    }
    if (tid == 0) { idx_out[b*KP + k] = ri[0]; vals[ri[0]] = -1e30f; }
    __syncthreads();
  }
}

__global__ __launch_bounds__(256) void gather_pair(const float* __restrict__ subf,
                                                   const float* __restrict__ objf,
                                                   const int* __restrict__ idx,
                                                   float* __restrict__ pc) {
  int bk = blockIdx.x;
  int b = bk / KP;
  int id = idx[bk];
  int spos = id / Nn, opos = id % Nn;
  const float* s = subf + ((size_t)b*Nn + spos)*Cc;
  const float* o = objf + ((size_t)b*Nn + opos)*Cc;
  float* dst = pc + (size_t)bk * (2*Cc);
  for (int c = threadIdx.x; c < Cc; c += 256) { dst[c] = s[c]; dst[Cc + c] = o[c]; }
}

__global__ void boxes_cat_kernel(const float* __restrict__ sb, const float* __restrict__ ob,
                                 float* __restrict__ out) {
  int i = blockIdx.x*256 + threadIdx.x;
  if (i >= TT*8) return;
  int c = i & 7, bk = i >> 3;
  out[i] = (c < 4) ? sb[bk*4 + c] : ob[bk*4 + (c - 4)];
}

__global__ __launch_bounds__(256) void ln_residual(const float* __restrict__ qin,
                                                   const float* __restrict__ delta,
                                                   const float* __restrict__ g,
                                                   const float* __restrict__ bta,
                                                   float* __restrict__ qout) {
  int t = blockIdx.x, c = threadIdx.x;
  float x = qin[(size_t)t*Cc + c] + delta[(size_t)t*Cc + c];
  __shared__ float red[256];
  red[c] = x; __syncthreads();
  for (int s = 128; s > 0; s >>= 1) { if (c < s) red[c] += red[c+s]; __syncthreads(); }
  float mean = red[0] * (1.f/Cc);
  __syncthreads();
  float d = x - mean;
  red[c] = d*d; __syncthreads();
  for (int s = 128; s > 0; s >>= 1) { if (c < s) red[c] += red[c+s]; __syncthreads(); }
  float var = red[0] * (1.f/Cc);
  qout[(size_t)t*Cc + c] = d * rsqrtf(var + LNEPS) * g[c] + bta[c];
}

// ---------------- self-attention: 100 keys, one tile ----------------
__global__ __launch_bounds__(512) void attn_sa(const float* __restrict__ qkv,
                                               float* __restrict__ out) {
  __shared__ float Kt[128][36];
  __shared__ float Vt[128][36];
  __shared__ float Qs[KP][DH];
  __shared__ float Ps[8][128];
  int bh = blockIdx.x; int b = bh >> 3, h = bh & 7;
  int tid = threadIdx.x;
  const float scale = 0.17677669529663687f;
  const size_t base = (size_t)b * KP * (3*Cc);
  for (int i = tid; i < KP*DH; i += 512) {
    int q = i >> 5, d = i & 31;
    Qs[q][d] = qkv[base + (size_t)q*(3*Cc) + h*DH + d] * scale;
  }
  {
    int j = tid >> 2, qc = tid & 3;
    float kf[8], vf[8];
    if (j < KP) {
      const float* sk = qkv + base + (size_t)j*(3*Cc) + Cc   + h*DH + qc*8;
      const float* sv = qkv + base + (size_t)j*(3*Cc) + 2*Cc + h*DH + qc*8;
      #pragma unroll
      for (int e = 0; e < 8; ++e) { kf[e] = sk[e]; vf[e] = sv[e]; }
    } else {
      #pragma unroll
      for (int e = 0; e < 8; ++e) { kf[e] = 0.f; vf[e] = 0.f; }
    }
    ((float4*)Kt[j])[qc*2]   = make_float4(kf[0],kf[1],kf[2],kf[3]);
    ((float4*)Kt[j])[qc*2+1] = make_float4(kf[4],kf[5],kf[6],kf[7]);
    ((float4*)Vt[j])[qc*2]   = make_float4(vf[0],vf[1],vf[2],vf[3]);
    ((float4*)Vt[j])[qc*2+1] = make_float4(vf[4],vf[5],vf[6],vf[7]);
  }
  __syncthreads();
  int w = tid >> 6, lane = tid & 63;
  int d = lane & 31, half = lane >> 5;
  for (int q = w; q < KP; q += 8) {
    float s0 = 0.f, s1 = 0.f;
    #pragma unroll
    for (int c = 0; c < 8; ++c) {
      float4 k0 = ((const float4*)Kt[lane])[c];
      float4 k1 = ((const float4*)Kt[lane+64])[c];
      float4 qv = *(const float4*)&Qs[q][c*4];
      s0 += k0.x*qv.x + k0.y*qv.y + k0.z*qv.z + k0.w*qv.w;
      s1 += k1.x*qv.x + k1.y*qv.y + k1.z*qv.z + k1.w*qv.w;
    }
    if (lane >= KP) s0 = -1e30f;
    if (lane + 64 >= KP) s1 = -1e30f;
    float mx = fmaxf(s0, s1);
    #pragma unroll
    for (int m2 = 32; m2 > 0; m2 >>= 1) mx = fmaxf(mx, __shfl_xor(mx, m2));
    float p0 = (lane < KP)      ? expf(s0 - mx) : 0.f;
    float p1 = (lane + 64 < KP) ? expf(s1 - mx) : 0.f;
    float sm = p0 + p1;
    #pragma unroll
    for (int m2 = 32; m2 > 0; m2 >>= 1) sm += __shfl_xor(sm, m2);
    Ps[w][lane] = p0; Ps[w][lane+64] = p1;
    float pv = 0.f;
    for (int s = 0; s < 64; ++s) {
      int j = half*64 + s;
      pv += Ps[w][j] * Vt[j][d];
    }
    pv += __shfl_xor(pv, 32);
    if (lane < 32) out[((size_t)b*KP + q)*Cc + h*DH + d] = pv / sm;
  }
}

// ---------------- cross-attention: MFMA flash-decode ----------------
__global__ __launch_bounds__(256) void attn_ca_mfma(
    const bf16* __restrict__ qhH,   // [bh][100][32] pre-scaled
    const bf16* __restrict__ khH,   // [bh][4096][32]
    const bf16* __restrict__ vhH,   // [bh][4096][32]
    bf16* __restrict__ part,        // [bh][NCH][100][32]
    float2* __restrict__ ml)        // [bh][NCH][100]
{
  __shared__ unsigned short Qs[128][36];
  __shared__ unsigned short Ks[128][36];
  __shared__ unsigned short Vs[32][140];
  __shared__ unsigned short Ps[128][140];
  const int bx = blockIdx.x;
  const int bh = bx >> 2, ch = bx & 3;
  const int tid = threadIdx.x;
  const int w = tid >> 6, lane = tid & 63;
  const int lr = lane & 15, lg = lane >> 4;
  const int k0base = ch * (Mm / NCH);

  for (int i = tid; i < 128*4; i += 256) {
    int q = i >> 2, c = i & 3;
    uint4 v = make_uint4(0u,0u,0u,0u);
    if (q < KP) v = *(const uint4*)(qhH + ((size_t)bh*KP + q)*DH + c*8);
    *(uint2*)&Qs[q][c*8]     = make_uint2(v.x, v.y);
    *(uint2*)&Qs[q][c*8 + 4] = make_uint2(v.z, v.w);
  }
  __syncthreads();
  const int qt0 = w, qt1 = w + 4;
  FragU qf[2];
  qf[0].u2[0] = *(const uint2*)&Qs[qt0*16 + lr][lg*8];
  qf[0].u2[1] = *(const uint2*)&Qs[qt0*16 + lr][lg*8 + 4];
  qf[1].u2[0] = *(const uint2*)&Qs[qt1*16 + lr][lg*8];
  qf[1].u2[1] = *(const uint2*)&Qs[qt1*16 + lr][lg*8 + 4];

  f32x4 acc[2][2] = {};
  float mreg[2] = {-1e30f, -1e30f};
  float lreg[2] = {0.f, 0.f};

  for (int sc = 0; sc < (Mm/NCH)/SUBK; ++sc) {
    const int k0 = k0base + sc*SUBK;
    __syncthreads();
    #pragma unroll
    for (int i = tid; i < 128*4; i += 256) {
      int m = i >> 2, c = i & 3;
      uint4 v = *(const uint4*)(khH + ((size_t)bh*Mm + k0 + m)*DH + c*8);
      *(uint2*)&Ks[m][c*8]     = make_uint2(v.x, v.y);
      *(uint2*)&Ks[m][c*8 + 4] = make_uint2(v.z, v.w);
    }
    {
      int p2 = tid & 63, c = tid >> 6;
      uint4 v0 = *(const uint4*)(vhH + ((size_t)bh*Mm + k0 + 2*p2    )*DH + c*8);
      uint4 v1 = *(const uint4*)(vhH + ((size_t)bh*Mm + k0 + 2*p2 + 1)*DH + c*8);
      const unsigned short* a0 = (const unsigned short*)&v0;
      const unsigned short* a1 = (const unsigned short*)&v1;
      #pragma unroll
      for (int e = 0; e < 8; ++e) {
        int d = c*8 + e;
        *(unsigned int*)&Vs[d][2*p2] = (unsigned)a0[e] | ((unsigned)a1[e] << 16);
      }
    }
    __syncthreads();

    f32x4 sv[2][8];
    #pragma unroll
    for (int kt = 0; kt < 8; ++kt) {
      FragU kf;
      kf.u2[0] = *(const uint2*)&Ks[kt*16 + lr][lg*8];
      kf.u2[1] = *(const uint2*)&Ks[kt*16 + lr][lg*8 + 4];
      f32x4 z = {0.f, 0.f, 0.f, 0.f};
      sv[0][kt] = __builtin_amdgcn_mfma_f32_16x16x32_bf16(kf.s8, qf[0].s8, z, 0, 0, 0);
      sv[1][kt] = __builtin_amdgcn_mfma_f32_16x16x32_bf16(kf.s8, qf[1].s8, z, 0, 0, 0);
    }

    #pragma unroll
    for (int j = 0; j < 2; ++j) {
      int qrow = (j ? qt1 : qt0)*16 + lr;
      float mx = -1e30f;
      #pragma unroll
      for (int kt = 0; kt < 8; ++kt)
        mx = fmaxf(mx, fmaxf(fmaxf(sv[j][kt][0], sv[j][kt][1]),
                             fmaxf(sv[j][kt][2], sv[j][kt][3])));
      mx = fmaxf(mx, __shfl_xor(mx, 16));
      mx = fmaxf(mx, __shfl_xor(mx, 32));
      float newm = fmaxf(mreg[j], mx);
      float resc = __expf(mreg[j] - newm);
      mreg[j] = newm;
      float psum = 0.f;
      #pragma unroll
      for (int kt = 0; kt < 8; ++kt) {
        float p0 = __expf(sv[j][kt][0] - newm);
        float p1 = __expf(sv[j][kt][1] - newm);
        float p2 = __expf(sv[j][kt][2] - newm);
        float p3 = __expf(sv[j][kt][3] - newm);
        psum += (p0 + p1) + (p2 + p3);
        unsigned lo = pack2(p0, p1);
        unsigned hi = pack2(p2, p3);
        *(uint2*)&Ps[qrow][kt*16 + lg*4] = make_uint2(lo, hi);
      }
      psum += __shfl_xor(psum, 16);
      psum += __shfl_xor(psum, 32);
      lreg[j] = lreg[j]*resc + psum;
      #pragma unroll
      for (int dt = 0; dt < 2; ++dt)
        #pragma unroll
        for (int r = 0; r < 4; ++r) acc[j][dt][r] *= resc;
    }

    #pragma unroll
    for (int ks = 0; ks < 4; ++ks) {
      FragU vf[2], pf[2];
      #pragma unroll
      for (int dt = 0; dt < 2; ++dt) {
        vf[dt].u2[0] = *(const uint2*)&Vs[dt*16 + lr][ks*32 + lg*8];
        vf[dt].u2[1] = *(const uint2*)&Vs[dt*16 + lr][ks*32 + lg*8 + 4];
      }
      #pragma unroll
      for (int j = 0; j < 2; ++j) {
        int qrow = (j ? qt1 : qt0)*16 + lr;
        pf[j].u2[0] = *(const uint2*)&Ps[qrow][ks*32 + lg*8];
        pf[j].u2[1] = *(const uint2*)&Ps[qrow][ks*32 + lg*8 + 4];
      }
      #pragma unroll
      for (int j = 0; j < 2; ++j)
        #pragma unroll
        for (int dt = 0; dt < 2; ++dt)
          acc[j][dt] = __builtin_amdgcn_mfma_f32_16x16x32_bf16(vf[dt].s8, pf[j].s8,
                                                               acc[j][dt], 0, 0, 0);
    }
  }

  #pragma unroll
  for (int j = 0; j < 2; ++j) {
    int q = (j ? qt1 : qt0)*16 + lr;
    if (q < KP) {
      if (lg == 0) ml[((size_t)bh*NCH + ch)*KP + q] = make_float2(mreg[j], lreg[j]);
      #pragma unroll
      for (int dt = 0; dt < 2; ++dt)
        #pragma unroll
        for (int r = 0; r < 4; ++r) {
          int d = dt*16 + lg*4 + r;
          part[(((size_t)bh*NCH + ch)*KP + q)*DH + d] = __float2bfloat16(acc[j][dt][r]);
        }
    }
  }
}

__global__ __launch_bounds__(256) void ca_combine(const bf16* __restrict__ part,
                                                  const float2* __restrict__ ml,
                                                  float* __restrict__ attn_o) {
  int idx = blockIdx.x*256 + threadIdx.x;
  if (idx >= Bb*Hh*KP*DH) return;
  int d = idx & 31;
  int q = (idx >> 5) % KP;
  int bh = idx / (KP*DH);
  int b = bh >> 3, h = bh & 7;
  float m0 = -1e30f;
  float2 mls[NCH];
  #pragma unroll
  for (int c = 0; c < NCH; ++c) {
    mls[c] = ml[((size_t)bh*NCH + c)*KP + q];
    m0 = fmaxf(m0, mls[c].x);
  }
  float L = 0.f, O = 0.f;
  #pragma unroll
  for (int c = 0; c < NCH; ++c) {
    float wgt = __expf(mls[c].x - m0);
    L += mls[c].y * wgt;
    O += __bfloat162float(part[(((size_t)bh*NCH + c)*KP + q)*DH + d]) * wgt;
  }
  attn_o[((size_t)b*KP + q)*Cc + h*DH + d] = O / L;
}

// ---------------- host ----------------
extern "C" void kernel_launch(void* const* d_in, const int* in_sizes, int n_in,
                              void* d_out, int out_size, void* d_ws, size_t ws_size,
                              hipStream_t stream) {
  auto in = [&](int i) { return (const float*)d_in[i]; };
  const float* hs        = in(0);
  const float* mem       = in(1);
  const float* mem_pos   = in(2);
  const float* sub_boxes = in(3);
  const float* obj_boxes = in(4);
  const float* su_w1 = in(5),  *su_b1 = in(6),  *su_w2 = in(7),  *su_b2 = in(8);
  const float* ou_w1 = in(9),  *ou_b1 = in(10), *ou_w2 = in(11), *ou_b2 = in(12);
  const float* pm_w1 = in(13), *pm_b1 = in(14), *pm_w2 = in(15), *pm_b2 = in(16);
  const float* sp_w1 = in(17), *sp_b1 = in(18), *sp_w2 = in(19), *sp_b2 = in(20);
  const float* sa_in_w = in(21),  *sa_in_b = in(22), *sa_out_w = in(23), *sa_out_b = in(24);
  const float* ca_in_w = in(25),  *ca_in_b = in(26), *ca_out_w = in(27), *ca_out_b = in(28);
  const float* l1_w = in(29), *l1_b = in(30), *l2_w = in(31), *l2_b = in(32);
  const float* n1_g = in(33), *n1_b = in(34), *n2_g = in(35), *n2_b = in(36);
  const float* n3_g = in(37), *n3_b = in(38);

  char* wsp = (char*)d_ws;
  auto alloc = [&](size_t bytes) { char* p = wsp; wsp += (bytes + 255) & ~(size_t)255; return p; };
  bf16* khH = (bf16*)alloc((size_t)Bb*Mm*Cc*2);
  bf16* vhH = (bf16*)alloc((size_t)Bb*Mm*Cc*2);
  bf16* qhH = (bf16*)alloc((size_t)TT*Cc*2);
  bf16* part = (bf16*)alloc((size_t)Bb*Hh*NCH*KP*DH*2);
  float2* mlbuf = (float2*)alloc((size_t)Bb*Hh*NCH*KP*8);
  // bf16 weights
  bf16* sawb = (bf16*)alloc((size_t)Ll*3*Cc*Cc*2);
  bf16* cawb = (bf16*)alloc((size_t)Ll*3*Cc*Cc*2);
  bf16* sowb = (bf16*)alloc((size_t)Ll*Cc*Cc*2);
  bf16* cowb = (bf16*)alloc((size_t)Ll*Cc*Cc*2);
  bf16* l1wb = (bf16*)alloc((size_t)Ll*Ff*Cc*2);
  bf16* l2wb = (bf16*)alloc((size_t)Ll*Cc*Ff*2);
  float* subf    = (float*)alloc((size_t)Bb*Nn*Cc*4);
  float* objf    = (float*)alloc((size_t)Bb*Nn*Cc*4);
  float* sub_emb = (float*)alloc((size_t)Bb*Nn*Cc*4);
  float* obj_emb = (float*)alloc((size_t)Bb*Nn*Cc*4);
  float* embh    = (float*)alloc((size_t)TT*2*Cc*4);
  float* imp     = (float*)alloc((size_t)Bb*Nn*Nn*4);
  int*   idx     = (int*)  alloc((size_t)Bb*KP*4);
  float* pair_cat= (float*)alloc((size_t)TT*2*Cc*4);
  float* bxc     = (float*)alloc((size_t)TT*8*4);
  float* spb     = (float*)alloc((size_t)TT*Cc*4);
  float* qbuf    = (float*)alloc((size_t)TT*Cc*4);
  float* qkv     = (float*)alloc((size_t)TT*3*Cc*4);
  float* attn_o  = (float*)alloc((size_t)TT*Cc*4);
  float* proj    = (float*)alloc((size_t)TT*Cc*4);
  bf16*  ffnb    = (bf16*)alloc((size_t)TT*Ff*2);

  // weight conversion (once per launch; deterministic)
  auto CV = [&](const float* src, bf16* dst, size_t n) {
    int n4 = (int)(n / 4);
    cvt_f2b<<<(n4 + 255)/256, 256, 0, stream>>>(src, dst, n4);
  };
  CV(sa_in_w, sawb, (size_t)Ll*3*Cc*Cc);
  CV(ca_in_w, cawb, (size_t)Ll*3*Cc*Cc);
  CV(sa_out_w, sowb, (size_t)Ll*Cc*Cc);
  CV(ca_out_w, cowb, (size_t)Ll*Cc*Cc);
  CV(l1_w, l1wb, (size_t)Ll*Ff*Cc);
  CV(l2_w, l2wb, (size_t)Ll*Cc*Ff);

  auto GF = [&](const float* A, const float* Wt, const float* bias,
                float* out, int M, int N, int K, bool relu) {
    dim3 g((N + 63)/64, (M + 63)/64), t(256);
    if (relu) gemm_nt<true ><<<g, t, 0, stream>>>(A, Wt, bias, out, M, N, K);
    else      gemm_nt<false><<<g, t, 0, stream>>>(A, Wt, bias, out, M, N, K);
  };

  // MFMA GEMM dispatcher: AT 0/1, OM 0..3, RELU only with OM1
  auto GM = [&](const void* A, const float* A2, const bf16* W, const float* bias,
                void* out, int M, int N, int K, int AT, int OM, bool relu) {
    int blocks = (M >> 7) * (N >> 7);
    if (AT == 0) {
      if (OM == 0)      gemm_mfma<0,false,0><<<blocks, 256, 0, stream>>>(A, A2, W, bias, out, M, N, K);
      else if (OM == 1) {
        if (relu)       gemm_mfma<0,true ,1><<<blocks, 256, 0, stream>>>(A, A2, W, bias, out, M, N, K);
        else            gemm_mfma<0,false,1><<<blocks, 256, 0, stream>>>(A, A2, W, bias, out, M, N, K);
      }
      else if (OM == 2) gemm_mfma<0,false,2><<<blocks, 256, 0, stream>>>(A, A2, W, bias, out, M, N, K);
      else              gemm_mfma<0,false,3><<<blocks, 256, 0, stream>>>(A, A2, W, bias, out, M, N, K);
    } else {
      if (OM == 0)      gemm_mfma<1,false,0><<<blocks, 256, 0, stream>>>(A, A2, W, bias, out, M, N, K);
      else              gemm_mfma<1,false,1><<<blocks, 256, 0, stream>>>(A, A2, W, bias, out, M, N, K);
    }
  };

  // ---- front-end (exact fp32: feeds top-k ordering) ----
  split_subobj<<<(Bb*Nn*Cc + 255)/256, 256, 0, stream>>>(hs, subf, objf);
  GF(subf, su_w1, su_b1, embh,    TT, Cc, Cc, true);
  GF(embh, su_w2, su_b2, sub_emb, TT, Cc, Cc, false);
  l2norm_kernel<<<TT, 256, 0, stream>>>(sub_emb);
  GF(objf, ou_w1, ou_b1, embh,    TT, Cc, Cc, true);
  GF(embh, ou_w2, ou_b2, obj_emb, TT, Cc, Cc, false);
  l2norm_kernel<<<TT, 256, 0, stream>>>(obj_emb);
  importance_kernel<<<Bb*Nn, 128, 0, stream>>>(sub_emb, obj_emb, imp);
  topk_kernel<<<Bb, 256, 0, stream>>>(imp, idx);
  gather_pair<<<TT, 256, 0, stream>>>(subf, objf, idx, pair_cat);
  GF(pair_cat, pm_w1, pm_b1, embh, TT, Cc, 2*Cc, true);
  GF(embh,     pm_w2, pm_b2, qbuf, TT, Cc, Cc,   false);
  boxes_cat_kernel<<<(TT*8 + 255)/256, 256, 0, stream>>>(sub_boxes, obj_boxes, bxc);
  GF(bxc,  sp_w1, sp_b1, embh, TT, Cc, 8,  true);
  GF(embh, sp_w2, sp_b2, spb,  TT, Cc, Cc, false);

  // ---- decoder layers (bf16 MFMA) ----
  for (int i = 0; i < Ll; ++i) {
    const bf16* sawL = sawb + (size_t)i*3*Cc*Cc;
    const bf16* cawL = cawb + (size_t)i*3*Cc*Cc;
    const float* sab = sa_in_b + (size_t)i*3*Cc;
    const float* cab = ca_in_b + (size_t)i*3*Cc;

    // self-attention (q_sp = q + sp fused into staging)
    GM(qbuf, spb, sawL, sab, qkv, TT, 3*Cc, Cc, 0, 0, false);
    attn_sa<<<Bb*Hh, 512, 0, stream>>>(qkv, attn_o);
    GM(attn_o, nullptr, sowb + (size_t)i*Cc*Cc, sa_out_b + (size_t)i*Cc, proj, TT, Cc, Cc, 0, 0, false);
    ln_residual<<<TT, 256, 0, stream>>>(qbuf, proj, n1_g + i*Cc, n1_b + i*Cc, qbuf);

    // cross-attention
    GM(qbuf, nullptr, cawL, cab, qhH, TT, Cc, Cc, 0, 3, false);
    GM(mem, mem_pos, cawL + (size_t)Cc*Cc,   cab + Cc,   khH, Bb*Mm, Cc, Cc, 0, 2, false);
    GM(mem, nullptr, cawL + (size_t)2*Cc*Cc, cab + 2*Cc, vhH, Bb*Mm, Cc, Cc, 0, 2, false);
    attn_ca_mfma<<<Bb*Hh*NCH, 256, 0, stream>>>(qhH, khH, vhH, part, mlbuf);
    ca_combine<<<(Bb*Hh*KP*DH + 255)/256, 256, 0, stream>>>(part, mlbuf, attn_o);
    GM(attn_o, nullptr, cowb + (size_t)i*Cc*Cc, ca_out_b + (size_t)i*Cc, proj, TT, Cc, Cc, 0, 0, false);
    ln_residual<<<TT, 256, 0, stream>>>(qbuf, proj, n2_g + i*Cc, n2_b + i*Cc, qbuf);

    // FFN
    GM(qbuf, nullptr, l1wb + (size_t)i*Ff*Cc, l1_b + (size_t)i*Ff, ffnb, TT, Ff, Cc, 0, 1, true);
    GM(ffnb, nullptr, l2wb + (size_t)i*Cc*Ff, l2_b + (size_t)i*Cc, proj, TT, Cc, Ff, 1, 0, false);
    float* qo = (i == Ll-1) ? (float*)d_out : qbuf;
    ln_residual<<<TT, 256, 0, stream>>>(qbuf, proj, n3_g + i*Cc, n3_b + i*Cc, qo);
  }
}

// Round 4
// 2390.934 us; speedup vs baseline: 7.3220x; 1.3035x over previous
//
#include <hip/hip_runtime.h>
#include <hip/hip_bf16.h>

#define Bb 32
#define Nn 100
#define Cc 256
#define Mm 4096
#define Ff 2048
#define Ll 6
#define Hh 8
#define DH 32
#define KP 100
#define TT (Bb*KP)
#define LNEPS 1e-5f
#define NCH 4
#define SUBK 128

typedef __hip_bfloat16 bf16;
typedef unsigned short ushort_t;
typedef __attribute__((ext_vector_type(8))) short short8v;
typedef __attribute__((ext_vector_type(4))) float f32x4;

union FragU { uint2 u2[2]; uint4 u4; short8v s8; };

__device__ __forceinline__ float bfu2f(unsigned short u) {
  union { unsigned u32; float f; } cv; cv.u32 = ((unsigned)u) << 16; return cv.f;
}
__device__ __forceinline__ unsigned short f2bf(float f) {
  union { float f; unsigned u; } c; c.f = f;
  unsigned r = c.u + 0x7FFF + ((c.u >> 16) & 1);
  return (unsigned short)(r >> 16);
}
__device__ __forceinline__ unsigned pack2(float a, float b) {
  return (unsigned)f2bf(a) | ((unsigned)f2bf(b) << 16);
}

// ---------------- bf16 MFMA GEMM: out = [A(+A2)] @ W^T + bias ----------------
// A: [M,K] (fp32 if AT==0, bf16 if AT==1) row-major. W: [N,K] bf16 row-major.
// M%128==0, N%128==0, K%64==0 required.
// OM: 0 fp32 row-major; 1 bf16 row-major; 2 bf16 head-major KV [b][h][4096][32];
//     3 bf16 head-major Q [b][h][100][32] scaled by 1/sqrt(32).
template<int AT, bool RELU, int OM>
__global__ __launch_bounds__(256) void gemm_mfma(
    const void* __restrict__ Av, const float* __restrict__ A2,
    const bf16* __restrict__ W, const float* __restrict__ bias,
    void* __restrict__ out, int M, int N, int K)
{
  __shared__ ushort_t As[128][72];
  __shared__ ushort_t Bs[128][72];
  const int mt = M >> 7, nt = N >> 7;
  const int nwg = mt * nt;
  const int g = blockIdx.x;
  const int xcd = g & 7, lid = g >> 3;
  const int q8 = nwg >> 3, r8 = nwg & 7;
  const int wgid = (xcd < r8 ? xcd*(q8+1) : r8*(q8+1) + (xcd - r8)*q8) + lid;
  const int ntile = wgid % nt, mtile = wgid / nt;
  const int bm = mtile << 7, bn = ntile << 7;
  const int tid = threadIdx.x;
  const int w = tid >> 6, lane = tid & 63;
  const int lr = lane & 15, lg = lane >> 4;
  const int wm = w >> 1, wn = w & 1;
  const float* Af = (const float*)Av;
  const bf16*  Ab = (const bf16*)Av;

  f32x4 acc[4][4] = {};

  for (int k0 = 0; k0 < K; k0 += 64) {
    __syncthreads();
    #pragma unroll
    for (int i = 0; i < 4; ++i) {
      int linear = i*256 + tid;
      int row = linear >> 3, c8 = linear & 7;
      uint4 packed;
      if (AT == 0) {
        const float* ap = Af + (size_t)(bm+row)*K + k0 + c8*8;
        float4 f0 = *(const float4*)ap;
        float4 f1 = *(const float4*)(ap+4);
        if (A2) {
          const float* ap2 = A2 + (size_t)(bm+row)*K + k0 + c8*8;
          float4 g0 = *(const float4*)ap2;
          float4 g1 = *(const float4*)(ap2+4);
          f0.x += g0.x; f0.y += g0.y; f0.z += g0.z; f0.w += g0.w;
          f1.x += g1.x; f1.y += g1.y; f1.z += g1.z; f1.w += g1.w;
        }
        packed.x = pack2(f0.x, f0.y); packed.y = pack2(f0.z, f0.w);
        packed.z = pack2(f1.x, f1.y); packed.w = pack2(f1.z, f1.w);
      } else {
        packed = *(const uint4*)(Ab + (size_t)(bm+row)*K + k0 + c8*8);
      }
      *(uint4*)&As[row][c8*8] = packed;
      uint4 wb = *(const uint4*)(W + (size_t)(bn+row)*K + k0 + c8*8);
      *(uint4*)&Bs[row][c8*8] = wb;
    }
    __syncthreads();
    #pragma unroll
    for (int kk = 0; kk < 64; kk += 32) {
      FragU a[4];
      #pragma unroll
      for (int mi = 0; mi < 4; ++mi)
        a[mi].u4 = *(const uint4*)&As[wm*64 + mi*16 + lr][kk + lg*8];
      #pragma unroll
      for (int ni = 0; ni < 4; ++ni) {
        FragU bfr;
        bfr.u4 = *(const uint4*)&Bs[wn*64 + ni*16 + lr][kk + lg*8];
        #pragma unroll
        for (int mi = 0; mi < 4; ++mi)
          acc[mi][ni] = __builtin_amdgcn_mfma_f32_16x16x32_bf16(a[mi].s8, bfr.s8,
                                                                acc[mi][ni], 0, 0, 0);
      }
    }
  }

  #pragma unroll
  for (int ni = 0; ni < 4; ++ni) {
    int col = bn + wn*64 + ni*16 + lr;
    float bv = bias ? bias[col] : 0.f;
    #pragma unroll
    for (int mi = 0; mi < 4; ++mi) {
      #pragma unroll
      for (int r = 0; r < 4; ++r) {
        int m = bm + wm*64 + mi*16 + lg*4 + r;
        float v = acc[mi][ni][r] + bv;
        if (RELU) v = fmaxf(v, 0.f);
        if (OM == 0) {
          ((float*)out)[(size_t)m*N + col] = v;
        } else if (OM == 1) {
          ((bf16*)out)[(size_t)m*N + col] = __float2bfloat16(v);
        } else if (OM == 2) {
          int bb = m >> 12, mm = m & 4095;
          int h = col >> 5, dd = col & 31;
          ((bf16*)out)[(((size_t)bb*Hh + h)*Mm + mm)*DH + dd] = __float2bfloat16(v);
        } else {
          int bb = m / KP, qq = m % KP;
          int h = col >> 5, dd = col & 31;
          ((bf16*)out)[(((size_t)bb*Hh + h)*KP + qq)*DH + dd] =
              __float2bfloat16(v * 0.17677669529663687f);
        }
      }
    }
  }
}

// fp32 -> bf16 weight conversion (n % 4 == 0)
__global__ void cvt_f2b(const float* __restrict__ in, bf16* __restrict__ out, int n4) {
  int i = blockIdx.x*256 + threadIdx.x;
  if (i >= n4) return;
  float4 f = *(const float4*)(in + (size_t)i*4);
  uint2 p; p.x = pack2(f.x, f.y); p.y = pack2(f.z, f.w);
  *(uint2*)(out + (size_t)i*4) = p;
}

// one-time pack: kb = bf16(mem + mem_pos), vb = bf16(mem)
__global__ void prep_mem(const float* __restrict__ mem, const float* __restrict__ mem_pos,
                         bf16* __restrict__ kb, bf16* __restrict__ vb, int n4) {
  int i = blockIdx.x*256 + threadIdx.x;
  if (i >= n4) return;
  float4 a = *(const float4*)(mem + (size_t)i*4);
  float4 p = *(const float4*)(mem_pos + (size_t)i*4);
  uint2 vv; vv.x = pack2(a.x, a.y); vv.y = pack2(a.z, a.w);
  uint2 kv; kv.x = pack2(a.x + p.x, a.y + p.y); kv.y = pack2(a.z + p.z, a.w + p.w);
  *(uint2*)(kb + (size_t)i*4) = kv;
  *(uint2*)(vb + (size_t)i*4) = vv;
}

// ---------------- fp32 GEMM (front-end only) ----------------
template<bool RELU>
__global__ __launch_bounds__(256) void gemm_nt(
    const float* __restrict__ A, const float* __restrict__ Wt,
    const float* __restrict__ bias, float* __restrict__ out, int M, int N, int K)
{
  __shared__ float As[16][68];
  __shared__ float Ws[16][68];
  const int bm = blockIdx.y * 64, bn = blockIdx.x * 64;
  const int tid = threadIdx.x;
  const int kk = tid & 15, rr = tid >> 4;
  const int tx = tid & 15, ty = tid >> 4;
  float acc[4][4] = {};
  for (int k0 = 0; k0 < K; k0 += 16) {
    #pragma unroll
    for (int p = 0; p < 4; ++p) {
      int m = rr + p*16;
      int row = bm + m;
      float av = 0.f, wv = 0.f;
      bool kin = (k0 + kk) < K;
      if (row < M && kin) av = A[(size_t)row * K + k0 + kk];
      int wrow = bn + m;
      if (wrow < N && kin) wv = Wt[(size_t)wrow * K + k0 + kk];
      As[kk][m] = av;
      Ws[kk][m] = wv;
    }
    __syncthreads();
    #pragma unroll
    for (int q = 0; q < 16; ++q) {
      float a[4], w[4];
      #pragma unroll
      for (int i = 0; i < 4; ++i) a[i] = As[q][ty*4 + i];
      #pragma unroll
      for (int j = 0; j < 4; ++j) w[j] = Ws[q][tx*4 + j];
      #pragma unroll
      for (int i = 0; i < 4; ++i)
        #pragma unroll
        for (int j = 0; j < 4; ++j) acc[i][j] += a[i] * w[j];
    }
    __syncthreads();
  }
  #pragma unroll
  for (int i = 0; i < 4; ++i) {
    int row = bm + ty*4 + i;
    if (row >= M) continue;
    #pragma unroll
    for (int j = 0; j < 4; ++j) {
      int col = bn + tx*4 + j;
      if (col >= N) continue;
      float v = acc[i][j];
      if (bias) v += bias[col];
      if (RELU) v = v > 0.f ? v : 0.f;
      out[(size_t)row*N + col] = v;
    }
  }
}

// ---------------- small kernels ----------------
__global__ void split_subobj(const float* __restrict__ hs,
                             float* __restrict__ subf, float* __restrict__ objf) {
  int i = blockIdx.x*256 + threadIdx.x;
  if (i >= Bb*Nn*Cc) return;
  int c = i % Cc, n = (i / Cc) % Nn, b = i / (Cc*Nn);
  subf[i] = hs[((size_t)b*2*Nn + 2*n    )*Cc + c];
  objf[i] = hs[((size_t)b*2*Nn + 2*n + 1)*Cc + c];
}

__global__ __launch_bounds__(256) void l2norm_kernel(float* __restrict__ x) {
  int t = blockIdx.x, c = threadIdx.x;
  float v = x[(size_t)t*Cc + c];
  __shared__ float red[256];
  red[c] = v*v; __syncthreads();
  for (int s = 128; s > 0; s >>= 1) { if (c < s) red[c] += red[c+s]; __syncthreads(); }
  float scale = 1.f / (sqrtf(red[0]) + 1e-6f);
  x[(size_t)t*Cc + c] = v * scale;
}

__global__ __launch_bounds__(128) void importance_kernel(const float* __restrict__ se,
                                                         const float* __restrict__ oe,
                                                         float* __restrict__ imp) {
  int b = blockIdx.x / Nn, n = blockIdx.x % Nn;
  int m = threadIdx.x;
  if (m >= Nn) return;
  const float* s = se + ((size_t)b*Nn + n)*Cc;
  const float* o = oe + ((size_t)b*Nn + m)*Cc;
  float acc = 0.f;
  for (int c = 0; c < Cc; ++c) acc += s[c] * o[c];
  imp[((size_t)b*Nn + n)*Nn + m] = acc;
}

// ---------------- exact top-k via radix select + bitonic sort ----------------
// One block (1024 thr) per batch. Order matches jax.lax.top_k:
// values descending, ties by ascending flat index.
__global__ __launch_bounds__(1024) void topk_kernel(const float* __restrict__ imp,
                                                    int* __restrict__ idx_out) {
  __shared__ unsigned mu[Nn*Nn];
  __shared__ unsigned hist[256];
  __shared__ unsigned prefix;
  __shared__ int remK;
  __shared__ unsigned long long keys[128];
  __shared__ unsigned tiebuf[256];
  __shared__ unsigned cnt_gt, cnt_tie;
  const int b = blockIdx.x, tid = threadIdx.x;
  const int NN = Nn*Nn;

  for (int i = tid; i < NN; i += 1024) {
    unsigned u = __float_as_uint(imp[(size_t)b*NN + i]);
    mu[i] = (u & 0x80000000u) ? ~u : (u | 0x80000000u);
  }
  if (tid == 0) { prefix = 0u; remK = KP; cnt_gt = 0u; cnt_tie = 0u; }
  __syncthreads();

  // 4 radix passes (high byte -> low byte) to find exact K-th threshold key
  for (int shift = 24; shift >= 0; shift -= 8) {
    if (tid < 256) hist[tid] = 0u;
    __syncthreads();
    unsigned pmask = (shift == 24) ? 0u : (0xFFFFFFFFu << (shift + 8));
    unsigned pref = prefix;
    for (int i = tid; i < NN; i += 1024) {
      unsigned v = mu[i];
      if ((v & pmask) == pref) atomicAdd(&hist[(v >> shift) & 0xFFu], 1u);
    }
    __syncthreads();
    if (tid == 0) {
      int rk = remK;
      unsigned sel = 0u;
      for (int bin = 255; bin >= 0; --bin) {
        int c = (int)hist[bin];
        if (c >= rk) { sel = (unsigned)bin; break; }
        rk -= c;
      }
      remK = rk;
      prefix = pref | (sel << shift);
    }
    __syncthreads();
  }

  const unsigned T = prefix;
  const int need = remK;   // how many ties at ==T to take (smallest indices)

  // collect strictly-greater keys and tie indices
  for (int i = tid; i < NN; i += 1024) {
    unsigned v = mu[i];
    if (v > T) {
      unsigned p = atomicAdd(&cnt_gt, 1u);
      keys[p] = ((unsigned long long)(~v) << 32) | (unsigned)i;
    } else if (v == T) {
      unsigned p = atomicAdd(&cnt_tie, 1u);
      if (p < 256u) tiebuf[p] = (unsigned)i;
    }
  }
  __syncthreads();
  const unsigned ngt = cnt_gt;            // == KP - need
  const unsigned nt_ = cnt_tie < 256u ? cnt_tie : 256u;

  // sort ties ascending by index (bitonic over 256, pad with UINT_MAX)
  for (int i = tid; i < 256; i += 1024) if (i >= (int)nt_) tiebuf[i] = 0xFFFFFFFFu;
  __syncthreads();
  for (int ksz = 2; ksz <= 256; ksz <<= 1) {
    for (int st = ksz >> 1; st > 0; st >>= 1) {
      if (tid < 128) {
        int i = ((tid & ~(st-1)) << 1) | (tid & (st-1));
        int j = i | st;
        bool up = ((i & ksz) == 0);
        unsigned a = tiebuf[i], c = tiebuf[j];
        if ((a > c) == up) { tiebuf[i] = c; tiebuf[j] = a; }
      }
      __syncthreads();
    }
  }
  // append `need` smallest tie indices; pad keys to 128
  for (int t = tid; t < need; t += 1024)
    keys[ngt + t] = ((unsigned long long)(~T) << 32) | tiebuf[t];
  for (int i = tid; i < 128; i += 1024)
    if (i >= KP) keys[i] = 0xFFFFFFFFFFFFFFFFull;
  __syncthreads();

  // bitonic sort 128 keys ascending => (value desc, index asc)
  for (int ksz = 2; ksz <= 128; ksz <<= 1) {
    for (int st = ksz >> 1; st > 0; st >>= 1) {
      if (tid < 64) {
        int i = ((tid & ~(st-1)) << 1) | (tid & (st-1));
        int j = i | st;
        bool up = ((i & ksz) == 0);
        unsigned long long a = keys[i], c = keys[j];
        if ((a > c) == up) { keys[i] = c; keys[j] = a; }
      }
      __syncthreads();
    }
  }
  if (tid < KP) idx_out[b*KP + tid] = (int)(keys[tid] & 0xFFFFFFFFu);
}

__global__ __launch_bounds__(256) void gather_pair(const float* __restrict__ subf,
                                                   const float* __restrict__ objf,
                                                   const int* __restrict__ idx,
                                                   float* __restrict__ pc) {
  int bk = blockIdx.x;
  int b = bk / KP;
  int id = idx[bk];
  int spos = id / Nn, opos = id % Nn;
  const float* s = subf + ((size_t)b*Nn + spos)*Cc;
  const float* o = objf + ((size_t)b*Nn + opos)*Cc;
  float* dst = pc + (size_t)bk * (2*Cc);
  for (int c = threadIdx.x; c < Cc; c += 256) { dst[c] = s[c]; dst[Cc + c] = o[c]; }
}

__global__ void boxes_cat_kernel(const float* __restrict__ sb, const float* __restrict__ ob,
                                 float* __restrict__ out) {
  int i = blockIdx.x*256 + threadIdx.x;
  if (i >= TT*8) return;
  int c = i & 7, bk = i >> 3;
  out[i] = (c < 4) ? sb[bk*4 + c] : ob[bk*4 + (c - 4)];
}

__global__ __launch_bounds__(256) void ln_residual(const float* __restrict__ qin,
                                                   const float* __restrict__ delta,
                                                   const float* __restrict__ g,
                                                   const float* __restrict__ bta,
                                                   float* __restrict__ qout) {
  int t = blockIdx.x, c = threadIdx.x;
  float x = qin[(size_t)t*Cc + c] + delta[(size_t)t*Cc + c];
  __shared__ float red[256];
  red[c] = x; __syncthreads();
  for (int s = 128; s > 0; s >>= 1) { if (c < s) red[c] += red[c+s]; __syncthreads(); }
  float mean = red[0] * (1.f/Cc);
  __syncthreads();
  float d = x - mean;
  red[c] = d*d; __syncthreads();
  for (int s = 128; s > 0; s >>= 1) { if (c < s) red[c] += red[c+s]; __syncthreads(); }
  float var = red[0] * (1.f/Cc);
  qout[(size_t)t*Cc + c] = d * rsqrtf(var + LNEPS) * g[c] + bta[c];
}

// ---------------- self-attention: 100 keys, one tile ----------------
__global__ __launch_bounds__(512) void attn_sa(const float* __restrict__ qkv,
                                               float* __restrict__ out) {
  __shared__ float Kt[128][36];
  __shared__ float Vt[128][36];
  __shared__ float Qs[KP][DH];
  __shared__ float Ps[8][128];
  int bh = blockIdx.x; int b = bh >> 3, h = bh & 7;
  int tid = threadIdx.x;
  const float scale = 0.17677669529663687f;
  const size_t base = (size_t)b * KP * (3*Cc);
  for (int i = tid; i < KP*DH; i += 512) {
    int q = i >> 5, d = i & 31;
    Qs[q][d] = qkv[base + (size_t)q*(3*Cc) + h*DH + d] * scale;
  }
  {
    int j = tid >> 2, qc = tid & 3;
    float kf[8], vf[8];
    if (j < KP) {
      const float* sk = qkv + base + (size_t)j*(3*Cc) + Cc   + h*DH + qc*8;
      const float* sv = qkv + base + (size_t)j*(3*Cc) + 2*Cc + h*DH + qc*8;
      #pragma unroll
      for (int e = 0; e < 8; ++e) { kf[e] = sk[e]; vf[e] = sv[e]; }
    } else {
      #pragma unroll
      for (int e = 0; e < 8; ++e) { kf[e] = 0.f; vf[e] = 0.f; }
    }
    ((float4*)Kt[j])[qc*2]   = make_float4(kf[0],kf[1],kf[2],kf[3]);
    ((float4*)Kt[j])[qc*2+1] = make_float4(kf[4],kf[5],kf[6],kf[7]);
    ((float4*)Vt[j])[qc*2]   = make_float4(vf[0],vf[1],vf[2],vf[3]);
    ((float4*)Vt[j])[qc*2+1] = make_float4(vf[4],vf[5],vf[6],vf[7]);
  }
  __syncthreads();
  int w = tid >> 6, lane = tid & 63;
  int d = lane & 31, half = lane >> 5;
  for (int q = w; q < KP; q += 8) {
    float s0 = 0.f, s1 = 0.f;
    #pragma unroll
    for (int c = 0; c < 8; ++c) {
      float4 k0 = ((const float4*)Kt[lane])[c];
      float4 k1 = ((const float4*)Kt[lane+64])[c];
      float4 qv = *(const float4*)&Qs[q][c*4];
      s0 += k0.x*qv.x + k0.y*qv.y + k0.z*qv.z + k0.w*qv.w;
      s1 += k1.x*qv.x + k1.y*qv.y + k1.z*qv.z + k1.w*qv.w;
    }
    if (lane >= KP) s0 = -1e30f;
    if (lane + 64 >= KP) s1 = -1e30f;
    float mx = fmaxf(s0, s1);
    #pragma unroll
    for (int m2 = 32; m2 > 0; m2 >>= 1) mx = fmaxf(mx, __shfl_xor(mx, m2));
    float p0 = (lane < KP)      ? expf(s0 - mx) : 0.f;
    float p1 = (lane + 64 < KP) ? expf(s1 - mx) : 0.f;
    float sm = p0 + p1;
    #pragma unroll
    for (int m2 = 32; m2 > 0; m2 >>= 1) sm += __shfl_xor(sm, m2);
    Ps[w][lane] = p0; Ps[w][lane+64] = p1;
    float pv = 0.f;
    for (int s = 0; s < 64; ++s) {
      int j = half*64 + s;
      pv += Ps[w][j] * Vt[j][d];
    }
    pv += __shfl_xor(pv, 32);
    if (lane < 32) out[((size_t)b*KP + q)*Cc + h*DH + d] = pv / sm;
  }
}

// ---------------- cross-attention: MFMA flash-decode ----------------
__global__ __launch_bounds__(256) void attn_ca_mfma(
    const bf16* __restrict__ qhH,   // [bh][100][32] pre-scaled
    const bf16* __restrict__ khH,   // [bh][4096][32]
    const bf16* __restrict__ vhH,   // [bh][4096][32]
    bf16* __restrict__ part,        // [bh][NCH][100][32]
    float2* __restrict__ ml)        // [bh][NCH][100]
{
  __shared__ unsigned short Qs[128][36];
  __shared__ unsigned short Ks[128][36];
  __shared__ unsigned short Vs[32][140];
  __shared__ unsigned short Ps[128][140];
  const int bx = blockIdx.x;
  const int bh = bx >> 2, ch = bx & 3;
  const int tid = threadIdx.x;
  const int w = tid >> 6, lane = tid & 63;
  const int lr = lane & 15, lg = lane >> 4;
  const int k0base = ch * (Mm / NCH);

  for (int i = tid; i < 128*4; i += 256) {
    int q = i >> 2, c = i & 3;
    uint4 v = make_uint4(0u,0u,0u,0u);
    if (q < KP) v = *(const uint4*)(qhH + ((size_t)bh*KP + q)*DH + c*8);
    *(uint2*)&Qs[q][c*8]     = make_uint2(v.x, v.y);
    *(uint2*)&Qs[q][c*8 + 4] = make_uint2(v.z, v.w);
  }
  __syncthreads();
  const int qt0 = w, qt1 = w + 4;
  FragU qf[2];
  qf[0].u2[0] = *(const uint2*)&Qs[qt0*16 + lr][lg*8];
  qf[0].u2[1] = *(const uint2*)&Qs[qt0*16 + lr][lg*8 + 4];
  qf[1].u2[0] = *(const uint2*)&Qs[qt1*16 + lr][lg*8];
  qf[1].u2[1] = *(const uint2*)&Qs[qt1*16 + lr][lg*8 + 4];

  f32x4 acc[2][2] = {};
  float mreg[2] = {-1e30f, -1e30f};
  float lreg[2] = {0.f, 0.f};

  for (int sc = 0; sc < (Mm/NCH)/SUBK; ++sc) {
    const int k0 = k0base + sc*SUBK;
    __syncthreads();
    #pragma unroll
    for (int i = tid; i < 128*4; i += 256) {
      int m = i >> 2, c = i & 3;
      uint4 v = *(const uint4*)(khH + ((size_t)bh*Mm + k0 + m)*DH + c*8);
      *(uint2*)&Ks[m][c*8]     = make_uint2(v.x, v.y);
      *(uint2*)&Ks[m][c*8 + 4] = make_uint2(v.z, v.w);
    }
    {
      int p2 = tid & 63, c = tid >> 6;
      uint4 v0 = *(const uint4*)(vhH + ((size_t)bh*Mm + k0 + 2*p2    )*DH + c*8);
      uint4 v1 = *(const uint4*)(vhH + ((size_t)bh*Mm + k0 + 2*p2 + 1)*DH + c*8);
      const unsigned short* a0 = (const unsigned short*)&v0;
      const unsigned short* a1 = (const unsigned short*)&v1;
      #pragma unroll
      for (int e = 0; e < 8; ++e) {
        int d = c*8 + e;
        *(unsigned int*)&Vs[d][2*p2] = (unsigned)a0[e] | ((unsigned)a1[e] << 16);
      }
    }
    __syncthreads();

    f32x4 sv[2][8];
    #pragma unroll
    for (int kt = 0; kt < 8; ++kt) {
      FragU kf;
      kf.u2[0] = *(const uint2*)&Ks[kt*16 + lr][lg*8];
      kf.u2[1] = *(const uint2*)&Ks[kt*16 + lr][lg*8 + 4];
      f32x4 z = {0.f, 0.f, 0.f, 0.f};
      sv[0][kt] = __builtin_amdgcn_mfma_f32_16x16x32_bf16(kf.s8, qf[0].s8, z, 0, 0, 0);
      sv[1][kt] = __builtin_amdgcn_mfma_f32_16x16x32_bf16(kf.s8, qf[1].s8, z, 0, 0, 0);
    }

    #pragma unroll
    for (int j = 0; j < 2; ++j) {
      int qrow = (j ? qt1 : qt0)*16 + lr;
      float mx = -1e30f;
      #pragma unroll
      for (int kt = 0; kt < 8; ++kt)
        mx = fmaxf(mx, fmaxf(fmaxf(sv[j][kt][0], sv[j][kt][1]),
                             fmaxf(sv[j][kt][2], sv[j][kt][3])));
      mx = fmaxf(mx, __shfl_xor(mx, 16));
      mx = fmaxf(mx, __shfl_xor(mx, 32));
      float newm = fmaxf(mreg[j], mx);
      float resc = __expf(mreg[j] - newm);
      mreg[j] = newm;
      float psum = 0.f;
      #pragma unroll
      for (int kt = 0; kt < 8; ++kt) {
        float p0 = __expf(sv[j][kt][0] - newm);
        float p1 = __expf(sv[j][kt][1] - newm);
        float p2 = __expf(sv[j][kt][2] - newm);
        float p3 = __expf(sv[j][kt][3] - newm);
        psum += (p0 + p1) + (p2 + p3);
        unsigned lo = pack2(p0, p1);
        unsigned hi = pack2(p2, p3);
        *(uint2*)&Ps[qrow][kt*16 + lg*4] = make_uint2(lo, hi);
      }
      psum += __shfl_xor(psum, 16);
      psum += __shfl_xor(psum, 32);
      lreg[j] = lreg[j]*resc + psum;
      #pragma unroll
      for (int dt = 0; dt < 2; ++dt)
        #pragma unroll
        for (int r = 0; r < 4; ++r) acc[j][dt][r] *= resc;
    }

    #pragma unroll
    for (int ks = 0; ks < 4; ++ks) {
      FragU vf[2], pf[2];
      #pragma unroll
      for (int dt = 0; dt < 2; ++dt) {
        vf[dt].u2[0] = *(const uint2*)&Vs[dt*16 + lr][ks*32 + lg*8];
        vf[dt].u2[1] = *(const uint2*)&Vs[dt*16 + lr][ks*32 + lg*8 + 4];
      }
      #pragma unroll
      for (int j = 0; j < 2; ++j) {
        int qrow = (j ? qt1 : qt0)*16 + lr;
        pf[j].u2[0] = *(const uint2*)&Ps[qrow][ks*32 + lg*8];
        pf[j].u2[1] = *(const uint2*)&Ps[qrow][ks*32 + lg*8 + 4];
      }
      #pragma unroll
      for (int j = 0; j < 2; ++j)
        #pragma unroll
        for (int dt = 0; dt < 2; ++dt)
          acc[j][dt] = __builtin_amdgcn_mfma_f32_16x16x32_bf16(vf[dt].s8, pf[j].s8,
                                                               acc[j][dt], 0, 0, 0);
    }
  }

  #pragma unroll
  for (int j = 0; j < 2; ++j) {
    int q = (j ? qt1 : qt0)*16 + lr;
    if (q < KP) {
      if (lg == 0) ml[((size_t)bh*NCH + ch)*KP + q] = make_float2(mreg[j], lreg[j]);
      #pragma unroll
      for (int dt = 0; dt < 2; ++dt)
        #pragma unroll
        for (int r = 0; r < 4; ++r) {
          int d = dt*16 + lg*4 + r;
          part[(((size_t)bh*NCH + ch)*KP + q)*DH + d] = __float2bfloat16(acc[j][dt][r]);
        }
    }
  }
}

__global__ __launch_bounds__(256) void ca_combine(const bf16* __restrict__ part,
                                                  const float2* __restrict__ ml,
                                                  float* __restrict__ attn_o) {
  int idx = blockIdx.x*256 + threadIdx.x;
  if (idx >= Bb*Hh*KP*DH) return;
  int d = idx & 31;
  int q = (idx >> 5) % KP;
  int bh = idx / (KP*DH);
  int b = bh >> 3, h = bh & 7;
  float m0 = -1e30f;
  float2 mls[NCH];
  #pragma unroll
  for (int c = 0; c < NCH; ++c) {
    mls[c] = ml[((size_t)bh*NCH + c)*KP + q];
    m0 = fmaxf(m0, mls[c].x);
  }
  float L = 0.f, O = 0.f;
  #pragma unroll
  for (int c = 0; c < NCH; ++c) {
    float wgt = __expf(mls[c].x - m0);
    L += mls[c].y * wgt;
    O += __bfloat162float(part[(((size_t)bh*NCH + c)*KP + q)*DH + d]) * wgt;
  }
  attn_o[((size_t)b*KP + q)*Cc + h*DH + d] = O / L;
}

// ---------------- host ----------------
extern "C" void kernel_launch(void* const* d_in, const int* in_sizes, int n_in,
                              void* d_out, int out_size, void* d_ws, size_t ws_size,
                              hipStream_t stream) {
  auto in = [&](int i) { return (const float*)d_in[i]; };
  const float* hs        = in(0);
  const float* mem       = in(1);
  const float* mem_pos   = in(2);
  const float* sub_boxes = in(3);
  const float* obj_boxes = in(4);
  const float* su_w1 = in(5),  *su_b1 = in(6),  *su_w2 = in(7),  *su_b2 = in(8);
  const float* ou_w1 = in(9),  *ou_b1 = in(10), *ou_w2 = in(11), *ou_b2 = in(12);
  const float* pm_w1 = in(13), *pm_b1 = in(14), *pm_w2 = in(15), *pm_b2 = in(16);
  const float* sp_w1 = in(17), *sp_b1 = in(18), *sp_w2 = in(19), *sp_b2 = in(20);
  const float* sa_in_w = in(21),  *sa_in_b = in(22), *sa_out_w = in(23), *sa_out_b = in(24);
  const float* ca_in_w = in(25),  *ca_in_b = in(26), *ca_out_w = in(27), *ca_out_b = in(28);
  const float* l1_w = in(29), *l1_b = in(30), *l2_w = in(31), *l2_b = in(32);
  const float* n1_g = in(33), *n1_b = in(34), *n2_g = in(35), *n2_b = in(36);
  const float* n3_g = in(37), *n3_b = in(38);

  char* wsp = (char*)d_ws;
  auto alloc = [&](size_t bytes) { char* p = wsp; wsp += (bytes + 255) & ~(size_t)255; return p; };
  bf16* khH = (bf16*)alloc((size_t)Bb*Mm*Cc*2);
  bf16* vhH = (bf16*)alloc((size_t)Bb*Mm*Cc*2);
  bf16* kmem_b = (bf16*)alloc((size_t)Bb*Mm*Cc*2);
  bf16* vmem_b = (bf16*)alloc((size_t)Bb*Mm*Cc*2);
  bf16* qhH = (bf16*)alloc((size_t)TT*Cc*2);
  bf16* part = (bf16*)alloc((size_t)Bb*Hh*NCH*KP*DH*2);
  float2* mlbuf = (float2*)alloc((size_t)Bb*Hh*NCH*KP*8);
  bf16* sawb = (bf16*)alloc((size_t)Ll*3*Cc*Cc*2);
  bf16* cawb = (bf16*)alloc((size_t)Ll*3*Cc*Cc*2);
  bf16* sowb = (bf16*)alloc((size_t)Ll*Cc*Cc*2);
  bf16* cowb = (bf16*)alloc((size_t)Ll*Cc*Cc*2);
  bf16* l1wb = (bf16*)alloc((size_t)Ll*Ff*Cc*2);
  bf16* l2wb = (bf16*)alloc((size_t)Ll*Cc*Ff*2);
  float* subf    = (float*)alloc((size_t)Bb*Nn*Cc*4);
  float* objf    = (float*)alloc((size_t)Bb*Nn*Cc*4);
  float* sub_emb = (float*)alloc((size_t)Bb*Nn*Cc*4);
  float* obj_emb = (float*)alloc((size_t)Bb*Nn*Cc*4);
  float* embh    = (float*)alloc((size_t)TT*2*Cc*4);
  float* imp     = (float*)alloc((size_t)Bb*Nn*Nn*4);
  int*   idx     = (int*)  alloc((size_t)Bb*KP*4);
  float* pair_cat= (float*)alloc((size_t)TT*2*Cc*4);
  float* bxc     = (float*)alloc((size_t)TT*8*4);
  float* spb     = (float*)alloc((size_t)TT*Cc*4);
  float* qbuf    = (float*)alloc((size_t)TT*Cc*4);
  float* qkv     = (float*)alloc((size_t)TT*3*Cc*4);
  float* attn_o  = (float*)alloc((size_t)TT*Cc*4);
  float* proj    = (float*)alloc((size_t)TT*Cc*4);
  bf16*  ffnb    = (bf16*)alloc((size_t)TT*Ff*2);

  auto CV = [&](const float* src, bf16* dst, size_t n) {
    int n4 = (int)(n / 4);
    cvt_f2b<<<(n4 + 255)/256, 256, 0, stream>>>(src, dst, n4);
  };
  CV(sa_in_w, sawb, (size_t)Ll*3*Cc*Cc);
  CV(ca_in_w, cawb, (size_t)Ll*3*Cc*Cc);
  CV(sa_out_w, sowb, (size_t)Ll*Cc*Cc);
  CV(ca_out_w, cowb, (size_t)Ll*Cc*Cc);
  CV(l1_w, l1wb, (size_t)Ll*Ff*Cc);
  CV(l2_w, l2wb, (size_t)Ll*Cc*Ff);
  {
    int n4 = (int)((size_t)Bb*Mm*Cc/4);
    prep_mem<<<(n4 + 255)/256, 256, 0, stream>>>(mem, mem_pos, kmem_b, vmem_b, n4);
  }

  auto GF = [&](const float* A, const float* Wt, const float* bias,
                float* out, int M, int N, int K, bool relu) {
    dim3 g((N + 63)/64, (M + 63)/64), t(256);
    if (relu) gemm_nt<true ><<<g, t, 0, stream>>>(A, Wt, bias, out, M, N, K);
    else      gemm_nt<false><<<g, t, 0, stream>>>(A, Wt, bias, out, M, N, K);
  };

  auto GM = [&](const void* A, const float* A2, const bf16* W, const float* bias,
                void* out, int M, int N, int K, int AT, int OM, bool relu) {
    int blocks = (M >> 7) * (N >> 7);
    if (AT == 0) {
      if (OM == 0)      gemm_mfma<0,false,0><<<blocks, 256, 0, stream>>>(A, A2, W, bias, out, M, N, K);
      else if (OM == 1) {
        if (relu)       gemm_mfma<0,true ,1><<<blocks, 256, 0, stream>>>(A, A2, W, bias, out, M, N, K);
        else            gemm_mfma<0,false,1><<<blocks, 256, 0, stream>>>(A, A2, W, bias, out, M, N, K);
      }
      else if (OM == 2) gemm_mfma<0,false,2><<<blocks, 256, 0, stream>>>(A, A2, W, bias, out, M, N, K);
      else              gemm_mfma<0,false,3><<<blocks, 256, 0, stream>>>(A, A2, W, bias, out, M, N, K);
    } else {
      if (OM == 0)      gemm_mfma<1,false,0><<<blocks, 256, 0, stream>>>(A, A2, W, bias, out, M, N, K);
      else if (OM == 1) gemm_mfma<1,false,1><<<blocks, 256, 0, stream>>>(A, A2, W, bias, out, M, N, K);
      else              gemm_mfma<1,false,2><<<blocks, 256, 0, stream>>>(A, A2, W, bias, out, M, N, K);
    }
  };

  // ---- front-end (exact fp32: feeds top-k ordering) ----
  split_subobj<<<(Bb*Nn*Cc + 255)/256, 256, 0, stream>>>(hs, subf, objf);
  GF(subf, su_w1, su_b1, embh,    TT, Cc, Cc, true);
  GF(embh, su_w2, su_b2, sub_emb, TT, Cc, Cc, false);
  l2norm_kernel<<<TT, 256, 0, stream>>>(sub_emb);
  GF(objf, ou_w1, ou_b1, embh,    TT, Cc, Cc, true);
  GF(embh, ou_w2, ou_b2, obj_emb, TT, Cc, Cc, false);
  l2norm_kernel<<<TT, 256, 0, stream>>>(obj_emb);
  importance_kernel<<<Bb*Nn, 128, 0, stream>>>(sub_emb, obj_emb, imp);
  topk_kernel<<<Bb, 1024, 0, stream>>>(imp, idx);
  gather_pair<<<TT, 256, 0, stream>>>(subf, objf, idx, pair_cat);
  GF(pair_cat, pm_w1, pm_b1, embh, TT, Cc, 2*Cc, true);
  GF(embh,     pm_w2, pm_b2, qbuf, TT, Cc, Cc,   false);
  boxes_cat_kernel<<<(TT*8 + 255)/256, 256, 0, stream>>>(sub_boxes, obj_boxes, bxc);
  GF(bxc,  sp_w1, sp_b1, embh, TT, Cc, 8,  true);
  GF(embh, sp_w2, sp_b2, spb,  TT, Cc, Cc, false);

  // ---- decoder layers (bf16 MFMA) ----
  for (int i = 0; i < Ll; ++i) {
    const bf16* sawL = sawb + (size_t)i*3*Cc*Cc;
    const bf16* cawL = cawb + (size_t)i*3*Cc*Cc;
    const float* sab = sa_in_b + (size_t)i*3*Cc;
    const float* cab = ca_in_b + (size_t)i*3*Cc;

    // self-attention (q_sp = q + sp fused into staging)
    GM(qbuf, spb, sawL, sab, qkv, TT, 3*Cc, Cc, 0, 0, false);
    attn_sa<<<Bb*Hh, 512, 0, stream>>>(qkv, attn_o);
    GM(attn_o, nullptr, sowb + (size_t)i*Cc*Cc, sa_out_b + (size_t)i*Cc, proj, TT, Cc, Cc, 0, 0, false);
    ln_residual<<<TT, 256, 0, stream>>>(qbuf, proj, n1_g + i*Cc, n1_b + i*Cc, qbuf);

    // cross-attention (bf16 A for K/V projections)
    GM(qbuf, nullptr, cawL, cab, qhH, TT, Cc, Cc, 0, 3, false);
    GM(kmem_b, nullptr, cawL + (size_t)Cc*Cc,   cab + Cc,   khH, Bb*Mm, Cc, Cc, 1, 2, false);
    GM(vmem_b, nullptr, cawL + (size_t)2*Cc*Cc, cab + 2*Cc, vhH, Bb*Mm, Cc, Cc, 1, 2, false);
    attn_ca_mfma<<<Bb*Hh*NCH, 256, 0, stream>>>(qhH, khH, vhH, part, mlbuf);
    ca_combine<<<(Bb*Hh*KP*DH + 255)/256, 256, 0, stream>>>(part, mlbuf, attn_o);
    GM(attn_o, nullptr, cowb + (size_t)i*Cc*Cc, ca_out_b + (size_t)i*Cc, proj, TT, Cc, Cc, 0, 0, false);
    ln_residual<<<TT, 256, 0, stream>>>(qbuf, proj, n2_g + i*Cc, n2_b + i*Cc, qbuf);

    // FFN
    GM(qbuf, nullptr, l1wb + (size_t)i*Ff*Cc, l1_b + (size_t)i*Ff, ffnb, TT, Ff, Cc, 0, 1, true);
    GM(ffnb, nullptr, l2wb + (size_t)i*Cc*Ff, l2_b + (size_t)i*Cc, proj, TT, Cc, Ff, 1, 0, false);
    float* qo = (i == Ll-1) ? (float*)d_out : qbuf;
    ln_residual<<<TT, 256, 0, stream>>>(qbuf, proj, n3_g + i*Cc, n3_b + i*Cc, qo);
  }
}